// Round 6
// baseline (441.159 us; speedup 1.0000x reference)
//
#include <hip/hip_runtime.h>
#include <hip/hip_bf16.h>
#include <math.h>

#define B_SZ    2
#define LSEQ    2048
#define DMODEL  1024
#define DINNER  2048
#define DSTATE  16
#define DCONV   4
#define DTRANK  64

#define NCHUNK  64
#define CLEN    (LSEQ / NCHUNK)   // 32

#define KSPLIT  16                // GEMM3 split-K factor (K-chunk = 128)
#define NX      96                // DT_RANK + 2*DSTATE

typedef unsigned short u16;
typedef __bf16 bf16x8 __attribute__((ext_vector_type(8)));
typedef float  f32x4  __attribute__((ext_vector_type(4)));

static __device__ __forceinline__ float sigmoidf_(float x) {
    return 1.0f / (1.0f + __expf(-x));
}
static __device__ __forceinline__ u16 f2b(float f) {   // RNE f32 -> bf16
    unsigned int u = __float_as_uint(f);
    u = (u + 0x7fffu + ((u >> 16) & 1u)) >> 16;
    return (u16)u;
}
static __device__ __forceinline__ float b2f(u16 v) {
    return __uint_as_float(((unsigned int)v) << 16);
}

// ----------------------------------------------------------------------------
// Straight cast f32 -> bf16, 8 elems/thread.
// ----------------------------------------------------------------------------
__global__ __launch_bounds__(256) void cast_bf16(
    const float* __restrict__ in, u16* __restrict__ out, int n8)
{
    const int i = blockIdx.x * 256 + threadIdx.x;
    if (i >= n8) return;
    const float4* p = reinterpret_cast<const float4*>(in + (size_t)i * 8);
    float4 v0 = p[0], v1 = p[1];
    union { u16 u[8]; uint4 q; } r;
    r.u[0] = f2b(v0.x); r.u[1] = f2b(v0.y); r.u[2] = f2b(v0.z); r.u[3] = f2b(v0.w);
    r.u[4] = f2b(v1.x); r.u[5] = f2b(v1.y); r.u[6] = f2b(v1.z); r.u[7] = f2b(v1.w);
    reinterpret_cast<uint4*>(out)[i] = r.q;
}

// ----------------------------------------------------------------------------
// Transpose-cast: in f32 [R][C] -> out bf16 [C][R]. 32x32 LDS tiles.
// ----------------------------------------------------------------------------
__global__ __launch_bounds__(256) void castT_bf16(
    const float* __restrict__ in, u16* __restrict__ out, int R, int C)
{
    __shared__ float t[32][33];
    const int r0 = blockIdx.y * 32, c0 = blockIdx.x * 32;
    const int tr = threadIdx.x >> 3;
    const int tc4 = (threadIdx.x & 7) * 4;
    const float4 v = *reinterpret_cast<const float4*>(in + (size_t)(r0 + tr) * C + c0 + tc4);
    t[tr][tc4 + 0] = v.x; t[tr][tc4 + 1] = v.y; t[tr][tc4 + 2] = v.z; t[tr][tc4 + 3] = v.w;
    __syncthreads();
    union { u16 u[4]; uint2 q; } r;
    #pragma unroll
    for (int j = 0; j < 4; j++) r.u[j] = f2b(t[tc4 + j][tr]);
    *reinterpret_cast<uint2*>(out + (size_t)(c0 + tr) * R + r0 + tc4) = r.q;
}

// ----------------------------------------------------------------------------
// GEMM1 (m97 structure) with split epilogue:
//   acc = x @ W_in ; col < DINNER      -> xs_bf  = bf16(acc)
//                    col >= DINNER     -> zs_bf  = bf16(silu(acc))   (the gate)
// ----------------------------------------------------------------------------
__global__ __launch_bounds__(256) void gemm_bf16_split(
    const u16* __restrict__ A, const u16* __restrict__ Bt,
    u16* __restrict__ xs_bf, u16* __restrict__ zs_bf, int K)
{
    __shared__ u16 As[128 * 32];
    __shared__ u16 Bs[128 * 32];
    const int tid  = threadIdx.x;
    const int lane = tid & 63;
    const int wave = tid >> 6;
    const int wr = wave >> 1, wc = wave & 1;
    const int bm = blockIdx.y * 128, bn = blockIdx.x * 128;
    const int lhi = lane >> 4;
    const int llo = lane & 15;

    f32x4 acc[4][4] = {};

    for (int k0 = 0; k0 < K; k0 += 32) {
        #pragma unroll
        for (int c = 0; c < 2; ++c) {
            const int s   = c * 256 + wave * 64 + lane;
            const int row = s >> 2, seg = s & 3;
            const u16* ga = A  + (size_t)(bm + row) * K + k0 + seg * 8;
            const u16* gb = Bt + (size_t)(bn + row) * K + k0 + seg * 8;
            __builtin_amdgcn_global_load_lds(
                (const __attribute__((address_space(1))) void*)ga,
                (__attribute__((address_space(3))) void*)(As + (size_t)(c * 256 + wave * 64) * 8),
                16, 0, 0);
            __builtin_amdgcn_global_load_lds(
                (const __attribute__((address_space(1))) void*)gb,
                (__attribute__((address_space(3))) void*)(Bs + (size_t)(c * 256 + wave * 64) * 8),
                16, 0, 0);
        }
        __syncthreads();

        bf16x8 af[4], bfr[4];
        #pragma unroll
        for (int m = 0; m < 4; ++m)
            af[m] = *reinterpret_cast<const bf16x8*>(&As[(wr * 64 + m * 16 + llo) * 32 + lhi * 8]);
        #pragma unroll
        for (int n = 0; n < 4; ++n)
            bfr[n] = *reinterpret_cast<const bf16x8*>(&Bs[(wc * 64 + n * 16 + llo) * 32 + lhi * 8]);
        #pragma unroll
        for (int m = 0; m < 4; ++m)
            #pragma unroll
            for (int n = 0; n < 4; ++n)
                acc[m][n] = __builtin_amdgcn_mfma_f32_16x16x32_bf16(af[m], bfr[n], acc[m][n], 0, 0, 0);
        __syncthreads();
    }

    #pragma unroll
    for (int m = 0; m < 4; ++m) {
        const int row0 = bm + wr * 64 + m * 16 + lhi * 4;
        #pragma unroll
        for (int n = 0; n < 4; ++n) {
            const int col = bn + wc * 64 + n * 16 + llo;
            #pragma unroll
            for (int j = 0; j < 4; ++j) {
                float v = acc[m][n][j];
                if (col < DINNER) {
                    xs_bf[(size_t)(row0 + j) * DINNER + col] = f2b(v);
                } else {
                    v = v * sigmoidf_(v);   // silu(res) pre-gated
                    zs_bf[(size_t)(row0 + j) * DINNER + (col - DINNER)] = f2b(v);
                }
            }
        }
    }
}

// ----------------------------------------------------------------------------
// bf16 MFMA GEMM (m97 structure): C_f32[M][N] = A[M][K] @ Bt[N][K]^T  (GEMM6)
// ----------------------------------------------------------------------------
__global__ __launch_bounds__(256) void gemm_bf16_tn(
    const u16* __restrict__ A, const u16* __restrict__ Bt,
    float* __restrict__ C, int M, int N, int K, int ldc)
{
    __shared__ u16 As[128 * 32];
    __shared__ u16 Bs[128 * 32];
    const int tid  = threadIdx.x;
    const int lane = tid & 63;
    const int wave = tid >> 6;
    const int wr = wave >> 1, wc = wave & 1;
    const int bm = blockIdx.y * 128, bn = blockIdx.x * 128;
    const int lhi = lane >> 4;
    const int llo = lane & 15;

    f32x4 acc[4][4] = {};

    for (int k0 = 0; k0 < K; k0 += 32) {
        #pragma unroll
        for (int c = 0; c < 2; ++c) {
            const int s   = c * 256 + wave * 64 + lane;
            const int row = s >> 2, seg = s & 3;
            const u16* ga = A  + (size_t)(bm + row) * K + k0 + seg * 8;
            const u16* gb = Bt + (size_t)(bn + row) * K + k0 + seg * 8;
            __builtin_amdgcn_global_load_lds(
                (const __attribute__((address_space(1))) void*)ga,
                (__attribute__((address_space(3))) void*)(As + (size_t)(c * 256 + wave * 64) * 8),
                16, 0, 0);
            __builtin_amdgcn_global_load_lds(
                (const __attribute__((address_space(1))) void*)gb,
                (__attribute__((address_space(3))) void*)(Bs + (size_t)(c * 256 + wave * 64) * 8),
                16, 0, 0);
        }
        __syncthreads();

        bf16x8 af[4], bfr[4];
        #pragma unroll
        for (int m = 0; m < 4; ++m)
            af[m] = *reinterpret_cast<const bf16x8*>(&As[(wr * 64 + m * 16 + llo) * 32 + lhi * 8]);
        #pragma unroll
        for (int n = 0; n < 4; ++n)
            bfr[n] = *reinterpret_cast<const bf16x8*>(&Bs[(wc * 64 + n * 16 + llo) * 32 + lhi * 8]);
        #pragma unroll
        for (int m = 0; m < 4; ++m)
            #pragma unroll
            for (int n = 0; n < 4; ++n)
                acc[m][n] = __builtin_amdgcn_mfma_f32_16x16x32_bf16(af[m], bfr[n], acc[m][n], 0, 0, 0);
        __syncthreads();
    }

    #pragma unroll
    for (int m = 0; m < 4; ++m) {
        const int row0 = bm + wr * 64 + m * 16 + lhi * 4;
        #pragma unroll
        for (int n = 0; n < 4; ++n) {
            const int col = bn + wc * 64 + n * 16 + llo;
            #pragma unroll
            for (int j = 0; j < 4; ++j)
                C[(size_t)(row0 + j) * ldc + col] = acc[m][n][j];
        }
    }
}

// ----------------------------------------------------------------------------
// Causal depthwise conv (width 4, left pad 3) + bias + SiLU.
// xs bf16 in, u bf16 out. 8 channels per thread.
// ----------------------------------------------------------------------------
__global__ __launch_bounds__(256) void conv_silu_bf(
    const u16* __restrict__ xs, const float* __restrict__ conv_w,
    const float* __restrict__ conv_b, u16* __restrict__ u)
{
    const int g  = blockIdx.x * 256 + threadIdx.x;     // over (bl, d/8)
    const int d8 = (g & 255) * 8;
    const int bl = g >> 8;
    const int l  = bl & (LSEQ - 1);

    float4 wv[8];
    #pragma unroll
    for (int j = 0; j < 8; j++)
        wv[j] = *reinterpret_cast<const float4*>(conv_w + (size_t)(d8 + j) * DCONV);

    float acc[8];
    #pragma unroll
    for (int j = 0; j < 8; j++) acc[j] = conv_b[d8 + j];

    #pragma unroll
    for (int k = 0; k < DCONV; k++) {
        const int l2 = l - (DCONV - 1) + k;
        if (l2 < 0) continue;
        const uint4 q = *reinterpret_cast<const uint4*>(
            xs + (size_t)(bl - (DCONV - 1) + k) * DINNER + d8);
        const u16* e = reinterpret_cast<const u16*>(&q);
        #pragma unroll
        for (int j = 0; j < 8; j++) {
            const float w = (k == 0) ? wv[j].x : (k == 1) ? wv[j].y : (k == 2) ? wv[j].z : wv[j].w;
            acc[j] = fmaf(b2f(e[j]), w, acc[j]);
        }
    }
    union { u16 u[8]; uint4 q; } r;
    #pragma unroll
    for (int j = 0; j < 8; j++) {
        const float v = acc[j];
        r.u[j] = f2b(v * sigmoidf_(v));
    }
    *reinterpret_cast<uint4*>(u + (size_t)bl * DINNER + d8) = r.q;
}

// ----------------------------------------------------------------------------
// GEMM3 split-K: partial[s][M][96] = u[M, ks] @ W_x[ks, :96], u is bf16.
// ----------------------------------------------------------------------------
__global__ __launch_bounds__(256) void gemm3_splitk(
    const u16* __restrict__ ubf, const float* __restrict__ Wx,
    float* __restrict__ partial)
{
    __shared__ float us[64][65];     // +1 pad: kills conflict on us[r][kk]
    __shared__ float wsm[64][96];

    const int tid = threadIdx.x;
    const int r0 = blockIdx.x * 64;
    const int k0 = blockIdx.y * (DINNER / KSPLIT);   // 128-wide K slice

    const int orow = tid >> 2;
    const int oc0  = (tid & 3) * 24;

    float acc[24];
    #pragma unroll
    for (int j = 0; j < 24; j++) acc[j] = 0.f;

    for (int ks = 0; ks < DINNER / KSPLIT; ks += 64) {
        // stage u[64][64] (bf16 -> f32)
        {
            const int row = tid >> 2;
            const int c16 = (tid & 3) << 4;
            const uint4* src = reinterpret_cast<const uint4*>(
                ubf + (size_t)(r0 + row) * DINNER + k0 + ks + c16);
            const uint4 q0 = src[0], q1 = src[1];
            const u16* e0 = reinterpret_cast<const u16*>(&q0);
            const u16* e1 = reinterpret_cast<const u16*>(&q1);
            #pragma unroll
            for (int j = 0; j < 8; j++) us[row][c16 + j]     = b2f(e0[j]);
            #pragma unroll
            for (int j = 0; j < 8; j++) us[row][c16 + 8 + j] = b2f(e1[j]);
        }
        // stage W_x[64][96]
        #pragma unroll
        for (int j = 0; j < 6; j++) {
            const int fid = tid + j * 256;
            const int kr  = fid / 24;
            const int c4  = (fid % 24) * 4;
            *reinterpret_cast<float4*>(&wsm[kr][c4]) =
                *reinterpret_cast<const float4*>(Wx + (size_t)(k0 + ks + kr) * NX + c4);
        }
        __syncthreads();

        for (int kk = 0; kk < 64; ++kk) {
            const float uv = us[orow][kk];
            #pragma unroll
            for (int j = 0; j < 24; j++)
                acc[j] = fmaf(uv, wsm[kk][oc0 + j], acc[j]);
        }
        __syncthreads();
    }

    float* pp = partial + ((size_t)blockIdx.y * (B_SZ * LSEQ) + r0 + orow) * NX + oc0;
    #pragma unroll
    for (int j = 0; j < 24; j += 4)
        *reinterpret_cast<float4*>(pp + j) = make_float4(acc[j], acc[j+1], acc[j+2], acc[j+3]);
}

__global__ __launch_bounds__(256) void gemm3_reduce(
    const float* __restrict__ partial, float* __restrict__ xdbl)
{
    const int i = blockIdx.x * 256 + threadIdx.x;
    if (i >= B_SZ * LSEQ * NX / 4) return;
    float4 s = make_float4(0.f, 0.f, 0.f, 0.f);
    #pragma unroll
    for (int p = 0; p < KSPLIT; p++) {
        const float4 v = reinterpret_cast<const float4*>(
            partial + (size_t)p * (B_SZ * LSEQ) * NX)[i];
        s.x += v.x; s.y += v.y; s.z += v.z; s.w += v.w;
    }
    reinterpret_cast<float4*>(xdbl)[i] = s;
}

// ----------------------------------------------------------------------------
// Scan phase 1 + fused delta: delta = softplus(xdbl[:, :64] @ W_dt[:, d] + b_dt[d])
// computed in f32 (W_dt column held in 64 VGPRs, xdbl row loads are wave-uniform
// and L2-resident). Writes hend, Sd, and delta as bf16 for phase 3.
// ----------------------------------------------------------------------------
__global__ __launch_bounds__(256) void scan_phase1(
    const u16* __restrict__ ubf, const float* __restrict__ xdbl,
    const float* __restrict__ Wdt, const float* __restrict__ bdt,
    const float* __restrict__ A_log,
    float* __restrict__ hend, float* __restrict__ Sd, u16* __restrict__ delta_bf)
{
    const int idx = blockIdx.x * 256 + threadIdx.x;   // ((b*NCHUNK+c)*DINNER+d)
    const int d = idx & (DINNER - 1);
    const int c = (idx >> 11) & (NCHUNK - 1);
    const int b = idx >> 17;

    float w[DTRANK];
    #pragma unroll
    for (int k = 0; k < DTRANK; k++) w[k] = Wdt[(size_t)k * DINNER + d];
    const float bb = bdt[d];

    float a[DSTATE];
    #pragma unroll
    for (int n = 0; n < DSTATE; n++) a[n] = -__expf(A_log[d * DSTATE + n]);

    float h[DSTATE];
    #pragma unroll
    for (int n = 0; n < DSTATE; n++) h[n] = 0.f;
    float sd = 0.f;

    const int l0 = b * LSEQ + c * CLEN;
    for (int i = 0; i < CLEN; ++i) {
        const size_t r = (size_t)(l0 + i);
        const float* xr = xdbl + r * NX;

        // delta = softplus(dot64 + b)
        float t = bb;
        #pragma unroll
        for (int k = 0; k < DTRANK; k += 4) {
            const float4 v = *reinterpret_cast<const float4*>(xr + k);
            t = fmaf(w[k],     v.x, t);
            t = fmaf(w[k + 1], v.y, t);
            t = fmaf(w[k + 2], v.z, t);
            t = fmaf(w[k + 3], v.w, t);
        }
        const float dv = (t > 20.f) ? t : log1pf(__expf(t));
        sd += dv;
        delta_bf[r * DINNER + d] = f2b(dv);

        const float uv = b2f(ubf[r * DINNER + d]);

        float Bv[DSTATE];
        {
            const float4* bp = reinterpret_cast<const float4*>(xr + DTRANK);
            float4 q;
            q = bp[0]; Bv[0]=q.x;  Bv[1]=q.y;  Bv[2]=q.z;  Bv[3]=q.w;
            q = bp[1]; Bv[4]=q.x;  Bv[5]=q.y;  Bv[6]=q.z;  Bv[7]=q.w;
            q = bp[2]; Bv[8]=q.x;  Bv[9]=q.y;  Bv[10]=q.z; Bv[11]=q.w;
            q = bp[3]; Bv[12]=q.x; Bv[13]=q.y; Bv[14]=q.z; Bv[15]=q.w;
        }
        const float du = dv * uv;
        #pragma unroll
        for (int n = 0; n < DSTATE; n++)
            h[n] = fmaf(__expf(dv * a[n]), h[n], du * Bv[n]);
    }

    float* hp = hend + ((size_t)(b * DINNER + d) * NCHUNK + c) * DSTATE;
    #pragma unroll
    for (int n = 0; n < DSTATE; n += 4)
        *reinterpret_cast<float4*>(hp + n) = make_float4(h[n], h[n+1], h[n+2], h[n+3]);
    Sd[(size_t)(b * DINNER + d) * NCHUNK + c] = sd;
}

__global__ __launch_bounds__(256) void scan_phase2(
    float* __restrict__ hend, const float* __restrict__ Sd,
    const float* __restrict__ A_log)
{
    const int idx = blockIdx.x * 256 + threadIdx.x;
    if (idx >= B_SZ * DINNER * DSTATE) return;
    const int n = idx & (DSTATE - 1);
    const int d = (idx >> 4) & (DINNER - 1);
    const int b = idx >> 15;

    const float an = -__expf(A_log[d * DSTATE + n]);
    const size_t base = (size_t)(b * DINNER + d) * NCHUNK;
    float carry = 0.f;
    for (int c = 0; c < NCHUNK; ++c) {
        const float P = __expf(an * Sd[base + c]);
        const size_t off = (base + c) * DSTATE + n;
        const float tmp = hend[off];
        hend[off] = carry;
        carry = fmaf(P, carry, tmp);
    }
}

// ----------------------------------------------------------------------------
// Scan phase 3: rescan with true h_in; y = sum h*C + u*D; multiply pre-gated
// silu(res); emit bf16 y for GEMM6.
// ----------------------------------------------------------------------------
__global__ __launch_bounds__(256) void scan_phase3(
    const u16* __restrict__ delta_bf, const u16* __restrict__ ubf,
    const u16* __restrict__ zs_bf, const float* __restrict__ xdbl,
    const float* __restrict__ A_log, const float* __restrict__ Dp,
    const float* __restrict__ hin, u16* __restrict__ ybf)
{
    const int idx = blockIdx.x * 256 + threadIdx.x;
    const int d = idx & (DINNER - 1);
    const int c = (idx >> 11) & (NCHUNK - 1);
    const int b = idx >> 17;

    float a[DSTATE];
    #pragma unroll
    for (int n = 0; n < DSTATE; n++) a[n] = -__expf(A_log[d * DSTATE + n]);
    const float Dd = Dp[d];

    float h[DSTATE];
    {
        const float* hp = hin + ((size_t)(b * DINNER + d) * NCHUNK + c) * DSTATE;
        #pragma unroll
        for (int n = 0; n < DSTATE; n += 4) {
            const float4 t = *reinterpret_cast<const float4*>(hp + n);
            h[n] = t.x; h[n+1] = t.y; h[n+2] = t.z; h[n+3] = t.w;
        }
    }

    const int l0 = b * LSEQ + c * CLEN;
    for (int i = 0; i < CLEN; ++i) {
        const size_t r = (size_t)(l0 + i);
        const float dv = b2f(delta_bf[r * DINNER + d]);
        const float uv = b2f(ubf[r * DINNER + d]);

        const float4* bp = reinterpret_cast<const float4*>(xdbl + r * NX + DTRANK);
        float Bv[DSTATE], Cv[DSTATE];
        {
            float4 t;
            t = bp[0]; Bv[0]=t.x;  Bv[1]=t.y;  Bv[2]=t.z;  Bv[3]=t.w;
            t = bp[1]; Bv[4]=t.x;  Bv[5]=t.y;  Bv[6]=t.z;  Bv[7]=t.w;
            t = bp[2]; Bv[8]=t.x;  Bv[9]=t.y;  Bv[10]=t.z; Bv[11]=t.w;
            t = bp[3]; Bv[12]=t.x; Bv[13]=t.y; Bv[14]=t.z; Bv[15]=t.w;
            t = bp[4]; Cv[0]=t.x;  Cv[1]=t.y;  Cv[2]=t.z;  Cv[3]=t.w;
            t = bp[5]; Cv[4]=t.x;  Cv[5]=t.y;  Cv[6]=t.z;  Cv[7]=t.w;
            t = bp[6]; Cv[8]=t.x;  Cv[9]=t.y;  Cv[10]=t.z; Cv[11]=t.w;
            t = bp[7]; Cv[12]=t.x; Cv[13]=t.y; Cv[14]=t.z; Cv[15]=t.w;
        }

        const float du = dv * uv;
        float yv = 0.f;
        #pragma unroll
        for (int n = 0; n < DSTATE; n++) {
            h[n] = fmaf(__expf(dv * a[n]), h[n], du * Bv[n]);
            yv = fmaf(h[n], Cv[n], yv);
        }
        yv = fmaf(uv, Dd, yv);

        const float g = b2f(zs_bf[r * DINNER + d]);   // pre-gated silu(res)
        ybf[r * DINNER + d] = f2b(yv * g);
    }
}

// ----------------------------------------------------------------------------
extern "C" void kernel_launch(void* const* d_in, const int* in_sizes, int n_in,
                              void* d_out, int out_size, void* d_ws, size_t ws_size,
                              hipStream_t stream) {
    const float* x      = (const float*)d_in[0];
    const float* W_in   = (const float*)d_in[1];
    const float* conv_w = (const float*)d_in[2];
    const float* conv_b = (const float*)d_in[3];
    const float* W_x    = (const float*)d_in[4];
    const float* W_dt   = (const float*)d_in[5];
    const float* b_dt   = (const float*)d_in[6];
    const float* A_log  = (const float*)d_in[7];
    const float* Dp     = (const float*)d_in[8];
    const float* W_out  = (const float*)d_in[9];
    float* out = (float*)d_out;

    const int M = B_SZ * LSEQ;   // 4096

    // workspace layout (~128.6 MB total)
    float* ws    = (float*)d_ws;
    float* xdbl  = ws;                                          // [4096,96] f32
    float* hend  = xdbl + (size_t)M * NX;                       // [2,2048,64,16] f32 (16MB)
    float* Sd    = hend + (size_t)B_SZ * DINNER * NCHUNK * DSTATE; // [2,2048,64] f32
    float* part  = Sd   + (size_t)B_SZ * DINNER * NCHUNK;       // [16,4096,96] f32 (25MB)
    u16*   xs_bf = (u16*)(part + (size_t)KSPLIT * M * NX);      // [4096,2048] bf16 (16MB)
    u16*   zs_bf = xs_bf + (size_t)M * DINNER;                  // [4096,2048] bf16 (silu(res))
    u16*   u_bf  = zs_bf + (size_t)M * DINNER;                  // [4096,2048] bf16
    u16*   dl_bf = u_bf  + (size_t)M * DINNER;                  // [4096,2048] bf16 (delta)
    u16*   xbf   = dl_bf + (size_t)M * DINNER;                  // [4096,1024] bf16
    u16*   WinT  = xbf   + (size_t)M * DMODEL;                  // [4096,1024] bf16
    u16*   WoutT = WinT  + (size_t)M * DMODEL;                  // [1024,2048] bf16
    u16*   ybf   = xbf;                                         // aliases xbf+WinT (dead after GEMM1)

    dim3 blk(256);

    // 0) casts for GEMM1
    cast_bf16<<<dim3((M * DMODEL / 8) / 256), blk, 0, stream>>>(x, xbf, M * DMODEL / 8);
    castT_bf16<<<dim3((2 * DINNER) / 32, DMODEL / 32), blk, 0, stream>>>(
        W_in, WinT, DMODEL, 2 * DINNER);

    // 1) GEMM1: xs_bf + pre-gated zs_bf = silu(res), both bf16
    gemm_bf16_split<<<dim3((2 * DINNER) / 128, M / 128), blk, 0, stream>>>(
        xbf, WinT, xs_bf, zs_bf, DMODEL);

    // 2) u = silu(causal_conv(xs) + conv_b)  (bf16 in/out)
    conv_silu_bf<<<dim3((M * DINNER / 8) / 256), blk, 0, stream>>>(
        xs_bf, conv_w, conv_b, u_bf);

    // 3) xdbl = u @ W_x   (split-K, bf16 A)
    gemm3_splitk<<<dim3(M / 64, KSPLIT), blk, 0, stream>>>(u_bf, W_x, part);
    gemm3_reduce<<<dim3((M * NX / 4 + 255) / 256), blk, 0, stream>>>(part, xdbl);

    // 4+5) scan with fused delta (GEMM4 eliminated)
    scan_phase1<<<dim3((B_SZ * DINNER * NCHUNK) / 256), blk, 0, stream>>>(
        u_bf, xdbl, W_dt, b_dt, A_log, hend, Sd, dl_bf);
    scan_phase2<<<dim3((B_SZ * DINNER * DSTATE) / 256), blk, 0, stream>>>(
        hend, Sd, A_log);
    scan_phase3<<<dim3((B_SZ * DINNER * NCHUNK) / 256), blk, 0, stream>>>(
        dl_bf, u_bf, zs_bf, xdbl, A_log, Dp, hend, ybf);

    // 5b) W_out^T cast
    castT_bf16<<<dim3(DMODEL / 32, DINNER / 32), blk, 0, stream>>>(
        W_out, WoutT, DINNER, DMODEL);

    // 6) out = y @ W_out  (bf16 MFMA)
    gemm_bf16_tn<<<dim3(DMODEL / 128, M / 128), blk, 0, stream>>>(
        ybf, WoutT, out, M, DMODEL, DINNER, DMODEL);
}

// Round 7
// 408.811 us; speedup vs baseline: 1.0791x; 1.0791x over previous
//
#include <hip/hip_runtime.h>
#include <hip/hip_bf16.h>
#include <math.h>

#define B_SZ    2
#define LSEQ    2048
#define DMODEL  1024
#define DINNER  2048
#define DSTATE  16
#define DCONV   4
#define DTRANK  64

#define NCHUNK  64
#define CLEN    (LSEQ / NCHUNK)   // 32

#define KSPLIT  16                // GEMM3 split-K factor (K-chunk = 128)
#define NX      96                // DT_RANK + 2*DSTATE

typedef unsigned short u16;
typedef __bf16 bf16x8 __attribute__((ext_vector_type(8)));
typedef float  f32x4  __attribute__((ext_vector_type(4)));

static __device__ __forceinline__ float sigmoidf_(float x) {
    return 1.0f / (1.0f + __expf(-x));
}
static __device__ __forceinline__ u16 f2b(float f) {   // RNE f32 -> bf16
    unsigned int u = __float_as_uint(f);
    u = (u + 0x7fffu + ((u >> 16) & 1u)) >> 16;
    return (u16)u;
}
static __device__ __forceinline__ float b2f(u16 v) {
    return __uint_as_float(((unsigned int)v) << 16);
}

// ----------------------------------------------------------------------------
// Straight cast f32 -> bf16, 8 elems/thread.
// ----------------------------------------------------------------------------
__global__ __launch_bounds__(256) void cast_bf16(
    const float* __restrict__ in, u16* __restrict__ out, int n8)
{
    const int i = blockIdx.x * 256 + threadIdx.x;
    if (i >= n8) return;
    const float4* p = reinterpret_cast<const float4*>(in + (size_t)i * 8);
    float4 v0 = p[0], v1 = p[1];
    union { u16 u[8]; uint4 q; } r;
    r.u[0] = f2b(v0.x); r.u[1] = f2b(v0.y); r.u[2] = f2b(v0.z); r.u[3] = f2b(v0.w);
    r.u[4] = f2b(v1.x); r.u[5] = f2b(v1.y); r.u[6] = f2b(v1.z); r.u[7] = f2b(v1.w);
    reinterpret_cast<uint4*>(out)[i] = r.q;
}

// ----------------------------------------------------------------------------
// Transpose-cast: in f32 [R][C] -> out bf16 [C][R]. 32x32 LDS tiles.
// ----------------------------------------------------------------------------
__global__ __launch_bounds__(256) void castT_bf16(
    const float* __restrict__ in, u16* __restrict__ out, int R, int C)
{
    __shared__ float t[32][33];
    const int r0 = blockIdx.y * 32, c0 = blockIdx.x * 32;
    const int tr = threadIdx.x >> 3;
    const int tc4 = (threadIdx.x & 7) * 4;
    const float4 v = *reinterpret_cast<const float4*>(in + (size_t)(r0 + tr) * C + c0 + tc4);
    t[tr][tc4 + 0] = v.x; t[tr][tc4 + 1] = v.y; t[tr][tc4 + 2] = v.z; t[tr][tc4 + 3] = v.w;
    __syncthreads();
    union { u16 u[4]; uint2 q; } r;
    #pragma unroll
    for (int j = 0; j < 4; j++) r.u[j] = f2b(t[tc4 + j][tr]);
    *reinterpret_cast<uint2*>(out + (size_t)(c0 + tr) * R + r0 + tc4) = r.q;
}

// ----------------------------------------------------------------------------
// bf16 MFMA GEMM (m97 structure + T2 seg-swizzle), templated epilogue.
// C[M,N] = A[M,K] @ Bt[N,K]^T
//  EPI 0: C f32 -> Cf (ldc)
//  EPI 1: col<DINNER -> xs=bf16(acc); col>=DINNER -> zs=bf16(silu(acc))  [GEMM1]
//  EPI 2: o0 = bf16(softplus(acc + bias[col]))                          [GEMM4]
// Swizzle (rule #21, both sides): LDS stays linear; global SOURCE uses
// seg^((row>>1)&3); ds_read uses the same XOR -> 16 lanes span all 32 banks
// 2-way (free) instead of 8-way.
// ----------------------------------------------------------------------------
template<int EPI>
__global__ __launch_bounds__(256) void gemm_mfma(
    const u16* __restrict__ A, const u16* __restrict__ Bt,
    float* __restrict__ Cf, u16* __restrict__ o0, u16* __restrict__ o1,
    const float* __restrict__ bias, int M, int N, int K, int ldc)
{
    __shared__ u16 As[128 * 32];
    __shared__ u16 Bs[128 * 32];
    const int tid  = threadIdx.x;
    const int lane = tid & 63;
    const int wave = tid >> 6;
    const int wr = wave >> 1, wc = wave & 1;
    const int bm = blockIdx.y * 128, bn = blockIdx.x * 128;
    const int lhi = lane >> 4;
    const int llo = lane & 15;

    f32x4 acc[4][4] = {};

    // swizzled ds_read segment index: lhi ^ ((fragment_row>>1)&3) = lhi ^ ((llo>>1)&3)
    const int rs = (lhi ^ ((llo >> 1) & 3)) * 8;

    for (int k0 = 0; k0 < K; k0 += 32) {
        #pragma unroll
        for (int c = 0; c < 2; ++c) {
            const int s   = c * 256 + wave * 64 + lane;
            const int row = s >> 2, seg = s & 3;
            const int sseg = seg ^ ((row >> 1) & 3);    // inverse-swizzled source
            const u16* ga = A  + (size_t)(bm + row) * K + k0 + sseg * 8;
            const u16* gb = Bt + (size_t)(bn + row) * K + k0 + sseg * 8;
            __builtin_amdgcn_global_load_lds(
                (const __attribute__((address_space(1))) void*)ga,
                (__attribute__((address_space(3))) void*)(As + (size_t)(c * 256 + wave * 64) * 8),
                16, 0, 0);
            __builtin_amdgcn_global_load_lds(
                (const __attribute__((address_space(1))) void*)gb,
                (__attribute__((address_space(3))) void*)(Bs + (size_t)(c * 256 + wave * 64) * 8),
                16, 0, 0);
        }
        __syncthreads();

        bf16x8 af[4], bfr[4];
        #pragma unroll
        for (int m = 0; m < 4; ++m)
            af[m] = *reinterpret_cast<const bf16x8*>(&As[(wr * 64 + m * 16 + llo) * 32 + rs]);
        #pragma unroll
        for (int n = 0; n < 4; ++n)
            bfr[n] = *reinterpret_cast<const bf16x8*>(&Bs[(wc * 64 + n * 16 + llo) * 32 + rs]);
        #pragma unroll
        for (int m = 0; m < 4; ++m)
            #pragma unroll
            for (int n = 0; n < 4; ++n)
                acc[m][n] = __builtin_amdgcn_mfma_f32_16x16x32_bf16(af[m], bfr[n], acc[m][n], 0, 0, 0);
        __syncthreads();
    }

    #pragma unroll
    for (int m = 0; m < 4; ++m) {
        const int row0 = bm + wr * 64 + m * 16 + lhi * 4;
        #pragma unroll
        for (int n = 0; n < 4; ++n) {
            const int col = bn + wc * 64 + n * 16 + llo;
            #pragma unroll
            for (int j = 0; j < 4; ++j) {
                float v = acc[m][n][j];
                if (EPI == 0) {
                    Cf[(size_t)(row0 + j) * ldc + col] = v;
                } else if (EPI == 1) {
                    if (col < DINNER) {
                        o0[(size_t)(row0 + j) * DINNER + col] = f2b(v);
                    } else {
                        v = v * sigmoidf_(v);   // silu(res) pre-gated
                        o1[(size_t)(row0 + j) * DINNER + (col - DINNER)] = f2b(v);
                    }
                } else {
                    v += bias[col];
                    v = (v > 20.f) ? v : log1pf(__expf(v));   // softplus
                    o0[(size_t)(row0 + j) * ldc + col] = f2b(v);
                }
            }
        }
    }
}

// ----------------------------------------------------------------------------
// Causal depthwise conv (width 4, left pad 3) + bias + SiLU. bf16 in/out.
// ----------------------------------------------------------------------------
__global__ __launch_bounds__(256) void conv_silu_bf(
    const u16* __restrict__ xs, const float* __restrict__ conv_w,
    const float* __restrict__ conv_b, u16* __restrict__ u)
{
    const int g  = blockIdx.x * 256 + threadIdx.x;     // over (bl, d/8)
    const int d8 = (g & 255) * 8;
    const int bl = g >> 8;
    const int l  = bl & (LSEQ - 1);

    float4 wv[8];
    #pragma unroll
    for (int j = 0; j < 8; j++)
        wv[j] = *reinterpret_cast<const float4*>(conv_w + (size_t)(d8 + j) * DCONV);

    float acc[8];
    #pragma unroll
    for (int j = 0; j < 8; j++) acc[j] = conv_b[d8 + j];

    #pragma unroll
    for (int k = 0; k < DCONV; k++) {
        const int l2 = l - (DCONV - 1) + k;
        if (l2 < 0) continue;
        const uint4 q = *reinterpret_cast<const uint4*>(
            xs + (size_t)(bl - (DCONV - 1) + k) * DINNER + d8);
        const u16* e = reinterpret_cast<const u16*>(&q);
        #pragma unroll
        for (int j = 0; j < 8; j++) {
            const float w = (k == 0) ? wv[j].x : (k == 1) ? wv[j].y : (k == 2) ? wv[j].z : wv[j].w;
            acc[j] = fmaf(b2f(e[j]), w, acc[j]);
        }
    }
    union { u16 u[8]; uint4 q; } r;
    #pragma unroll
    for (int j = 0; j < 8; j++) {
        const float v = acc[j];
        r.u[j] = f2b(v * sigmoidf_(v));
    }
    *reinterpret_cast<uint4*>(u + (size_t)bl * DINNER + d8) = r.q;
}

// ----------------------------------------------------------------------------
// GEMM3 split-K: partial[s][M][96] = u[M, ks] @ W_x[ks, :96], u is bf16.
// ----------------------------------------------------------------------------
__global__ __launch_bounds__(256) void gemm3_splitk(
    const u16* __restrict__ ubf, const float* __restrict__ Wx,
    float* __restrict__ partial)
{
    __shared__ float us[64][65];
    __shared__ float wsm[64][96];

    const int tid = threadIdx.x;
    const int r0 = blockIdx.x * 64;
    const int k0 = blockIdx.y * (DINNER / KSPLIT);

    const int orow = tid >> 2;
    const int oc0  = (tid & 3) * 24;

    float acc[24];
    #pragma unroll
    for (int j = 0; j < 24; j++) acc[j] = 0.f;

    for (int ks = 0; ks < DINNER / KSPLIT; ks += 64) {
        {
            const int row = tid >> 2;
            const int c16 = (tid & 3) << 4;
            const uint4* src = reinterpret_cast<const uint4*>(
                ubf + (size_t)(r0 + row) * DINNER + k0 + ks + c16);
            const uint4 q0 = src[0], q1 = src[1];
            const u16* e0 = reinterpret_cast<const u16*>(&q0);
            const u16* e1 = reinterpret_cast<const u16*>(&q1);
            #pragma unroll
            for (int j = 0; j < 8; j++) us[row][c16 + j]     = b2f(e0[j]);
            #pragma unroll
            for (int j = 0; j < 8; j++) us[row][c16 + 8 + j] = b2f(e1[j]);
        }
        #pragma unroll
        for (int j = 0; j < 6; j++) {
            const int fid = tid + j * 256;
            const int kr  = fid / 24;
            const int c4  = (fid % 24) * 4;
            *reinterpret_cast<float4*>(&wsm[kr][c4]) =
                *reinterpret_cast<const float4*>(Wx + (size_t)(k0 + ks + kr) * NX + c4);
        }
        __syncthreads();

        for (int kk = 0; kk < 64; ++kk) {
            const float uv = us[orow][kk];
            #pragma unroll
            for (int j = 0; j < 24; j++)
                acc[j] = fmaf(uv, wsm[kk][oc0 + j], acc[j]);
        }
        __syncthreads();
    }

    float* pp = partial + ((size_t)blockIdx.y * (B_SZ * LSEQ) + r0 + orow) * NX + oc0;
    #pragma unroll
    for (int j = 0; j < 24; j += 4)
        *reinterpret_cast<float4*>(pp + j) = make_float4(acc[j], acc[j+1], acc[j+2], acc[j+3]);
}

// reduce partials -> xdbl f32 [M][96]; also emit bf16 copy of cols 0..63 (GEMM4 A)
__global__ __launch_bounds__(256) void gemm3_reduce(
    const float* __restrict__ partial, float* __restrict__ xdbl,
    u16* __restrict__ x64bf)
{
    const int i = blockIdx.x * 256 + threadIdx.x;   // float4 index over [M][96]
    if (i >= B_SZ * LSEQ * NX / 4) return;
    float4 s = make_float4(0.f, 0.f, 0.f, 0.f);
    #pragma unroll
    for (int p = 0; p < KSPLIT; p++) {
        const float4 v = reinterpret_cast<const float4*>(
            partial + (size_t)p * (B_SZ * LSEQ) * NX)[i];
        s.x += v.x; s.y += v.y; s.z += v.z; s.w += v.w;
    }
    reinterpret_cast<float4*>(xdbl)[i] = s;

    const int col4 = (i % 24) * 4;
    if (col4 < DTRANK) {
        const int row = i / 24;
        union { u16 u[4]; uint2 q; } r;
        r.u[0] = f2b(s.x); r.u[1] = f2b(s.y); r.u[2] = f2b(s.z); r.u[3] = f2b(s.w);
        *reinterpret_cast<uint2*>(x64bf + (size_t)row * DTRANK + col4) = r.q;
    }
}

// ----------------------------------------------------------------------------
// Chunk-parallel selective scan (3 phases). delta comes in as bf16 (dl_bf).
// ----------------------------------------------------------------------------
__global__ __launch_bounds__(256) void scan_phase1(
    const u16* __restrict__ dl_bf, const u16* __restrict__ ubf,
    const float* __restrict__ xdbl, const float* __restrict__ A_log,
    float* __restrict__ hend, float* __restrict__ Sd)
{
    const int idx = blockIdx.x * 256 + threadIdx.x;   // ((b*NCHUNK+c)*DINNER+d)
    const int d = idx & (DINNER - 1);
    const int c = (idx >> 11) & (NCHUNK - 1);
    const int b = idx >> 17;

    float a[DSTATE];
    #pragma unroll
    for (int n = 0; n < DSTATE; n++) a[n] = -__expf(A_log[d * DSTATE + n]);

    float h[DSTATE];
    #pragma unroll
    for (int n = 0; n < DSTATE; n++) h[n] = 0.f;
    float sd = 0.f;

    const int l0 = b * LSEQ + c * CLEN;
    for (int i = 0; i < CLEN; ++i) {
        const size_t r = (size_t)(l0 + i);
        const float dv = b2f(dl_bf[r * DINNER + d]);
        const float uv = b2f(ubf[r * DINNER + d]);
        sd += dv;
        float Bv[DSTATE];
        {
            const float4* bp = reinterpret_cast<const float4*>(xdbl + r * NX + DTRANK);
            float4 q;
            q = bp[0]; Bv[0]=q.x;  Bv[1]=q.y;  Bv[2]=q.z;  Bv[3]=q.w;
            q = bp[1]; Bv[4]=q.x;  Bv[5]=q.y;  Bv[6]=q.z;  Bv[7]=q.w;
            q = bp[2]; Bv[8]=q.x;  Bv[9]=q.y;  Bv[10]=q.z; Bv[11]=q.w;
            q = bp[3]; Bv[12]=q.x; Bv[13]=q.y; Bv[14]=q.z; Bv[15]=q.w;
        }
        const float du = dv * uv;
        #pragma unroll
        for (int n = 0; n < DSTATE; n++)
            h[n] = fmaf(__expf(dv * a[n]), h[n], du * Bv[n]);
    }

    float* hp = hend + ((size_t)(b * DINNER + d) * NCHUNK + c) * DSTATE;
    #pragma unroll
    for (int n = 0; n < DSTATE; n += 4)
        *reinterpret_cast<float4*>(hp + n) = make_float4(h[n], h[n+1], h[n+2], h[n+3]);
    Sd[(size_t)(b * DINNER + d) * NCHUNK + c] = sd;
}

__global__ __launch_bounds__(256) void scan_phase2(
    float* __restrict__ hend, const float* __restrict__ Sd,
    const float* __restrict__ A_log)
{
    const int idx = blockIdx.x * 256 + threadIdx.x;
    if (idx >= B_SZ * DINNER * DSTATE) return;
    const int n = idx & (DSTATE - 1);
    const int d = (idx >> 4) & (DINNER - 1);
    const int b = idx >> 15;

    const float an = -__expf(A_log[d * DSTATE + n]);
    const size_t base = (size_t)(b * DINNER + d) * NCHUNK;
    float carry = 0.f;
    for (int c = 0; c < NCHUNK; ++c) {
        const float P = __expf(an * Sd[base + c]);
        const size_t off = (base + c) * DSTATE + n;
        const float tmp = hend[off];
        hend[off] = carry;
        carry = fmaf(P, carry, tmp);
    }
}

__global__ __launch_bounds__(256) void scan_phase3(
    const u16* __restrict__ dl_bf, const u16* __restrict__ ubf,
    const u16* __restrict__ zs_bf, const float* __restrict__ xdbl,
    const float* __restrict__ A_log, const float* __restrict__ Dp,
    const float* __restrict__ hin, u16* __restrict__ ybf)
{
    const int idx = blockIdx.x * 256 + threadIdx.x;
    const int d = idx & (DINNER - 1);
    const int c = (idx >> 11) & (NCHUNK - 1);
    const int b = idx >> 17;

    float a[DSTATE];
    #pragma unroll
    for (int n = 0; n < DSTATE; n++) a[n] = -__expf(A_log[d * DSTATE + n]);
    const float Dd = Dp[d];

    float h[DSTATE];
    {
        const float* hp = hin + ((size_t)(b * DINNER + d) * NCHUNK + c) * DSTATE;
        #pragma unroll
        for (int n = 0; n < DSTATE; n += 4) {
            const float4 t = *reinterpret_cast<const float4*>(hp + n);
            h[n] = t.x; h[n+1] = t.y; h[n+2] = t.z; h[n+3] = t.w;
        }
    }

    const int l0 = b * LSEQ + c * CLEN;
    for (int i = 0; i < CLEN; ++i) {
        const size_t r = (size_t)(l0 + i);
        const float dv = b2f(dl_bf[r * DINNER + d]);
        const float uv = b2f(ubf[r * DINNER + d]);

        const float4* bp = reinterpret_cast<const float4*>(xdbl + r * NX + DTRANK);
        float Bv[DSTATE], Cv[DSTATE];
        {
            float4 t;
            t = bp[0]; Bv[0]=t.x;  Bv[1]=t.y;  Bv[2]=t.z;  Bv[3]=t.w;
            t = bp[1]; Bv[4]=t.x;  Bv[5]=t.y;  Bv[6]=t.z;  Bv[7]=t.w;
            t = bp[2]; Bv[8]=t.x;  Bv[9]=t.y;  Bv[10]=t.z; Bv[11]=t.w;
            t = bp[3]; Bv[12]=t.x; Bv[13]=t.y; Bv[14]=t.z; Bv[15]=t.w;
            t = bp[4]; Cv[0]=t.x;  Cv[1]=t.y;  Cv[2]=t.z;  Cv[3]=t.w;
            t = bp[5]; Cv[4]=t.x;  Cv[5]=t.y;  Cv[6]=t.z;  Cv[7]=t.w;
            t = bp[6]; Cv[8]=t.x;  Cv[9]=t.y;  Cv[10]=t.z; Cv[11]=t.w;
            t = bp[7]; Cv[12]=t.x; Cv[13]=t.y; Cv[14]=t.z; Cv[15]=t.w;
        }

        const float du = dv * uv;
        float yv = 0.f;
        #pragma unroll
        for (int n = 0; n < DSTATE; n++) {
            h[n] = fmaf(__expf(dv * a[n]), h[n], du * Bv[n]);
            yv = fmaf(h[n], Cv[n], yv);
        }
        yv = fmaf(uv, Dd, yv);

        const float g = b2f(zs_bf[r * DINNER + d]);   // pre-gated silu(res)
        ybf[r * DINNER + d] = f2b(yv * g);
    }
}

// ----------------------------------------------------------------------------
extern "C" void kernel_launch(void* const* d_in, const int* in_sizes, int n_in,
                              void* d_out, int out_size, void* d_ws, size_t ws_size,
                              hipStream_t stream) {
    const float* x      = (const float*)d_in[0];
    const float* W_in   = (const float*)d_in[1];
    const float* conv_w = (const float*)d_in[2];
    const float* conv_b = (const float*)d_in[3];
    const float* W_x    = (const float*)d_in[4];
    const float* W_dt   = (const float*)d_in[5];
    const float* b_dt   = (const float*)d_in[6];
    const float* A_log  = (const float*)d_in[7];
    const float* Dp     = (const float*)d_in[8];
    const float* W_out  = (const float*)d_in[9];
    float* out = (float*)d_out;

    const int M = B_SZ * LSEQ;   // 4096

    // workspace layout (~134 MB)
    float* ws     = (float*)d_ws;
    float* xdbl   = ws;                                           // [4096,96] f32
    float* hend   = xdbl + (size_t)M * NX;                        // [2,2048,64,16] f32
    float* Sd     = hend + (size_t)B_SZ * DINNER * NCHUNK * DSTATE;
    float* part   = Sd   + (size_t)B_SZ * DINNER * NCHUNK;        // [16,4096,96] f32
    u16*   xs_bf  = (u16*)(part + (size_t)KSPLIT * M * NX);       // [4096,2048] bf16
    u16*   zs_bf  = xs_bf + (size_t)M * DINNER;                   // [4096,2048] bf16
    u16*   u_bf   = zs_bf + (size_t)M * DINNER;                   // [4096,2048] bf16
    u16*   dl_bf  = u_bf  + (size_t)M * DINNER;                   // [4096,2048] bf16
    u16*   xbf    = dl_bf + (size_t)M * DINNER;                   // [4096,1024] bf16
    u16*   WinT   = xbf   + (size_t)M * DMODEL;                   // [4096,1024] bf16
    u16*   WoutT  = WinT  + (size_t)M * DMODEL;                   // [1024,2048] bf16
    u16*   x64bf  = WoutT + (size_t)DMODEL * DINNER;              // [4096,64] bf16
    u16*   WdtT   = x64bf + (size_t)M * DTRANK;                   // [2048,64] bf16
    u16*   ybf    = xbf;                                          // aliases xbf+WinT

    dim3 blk(256);

    // 0) casts for GEMM1
    cast_bf16<<<dim3((M * DMODEL / 8) / 256), blk, 0, stream>>>(x, xbf, M * DMODEL / 8);
    castT_bf16<<<dim3((2 * DINNER) / 32, DMODEL / 32), blk, 0, stream>>>(
        W_in, WinT, DMODEL, 2 * DINNER);

    // 1) GEMM1: xs_bf + pre-gated zs_bf, both bf16
    gemm_mfma<1><<<dim3((2 * DINNER) / 128, M / 128), blk, 0, stream>>>(
        xbf, WinT, nullptr, xs_bf, zs_bf, nullptr, M, 2 * DINNER, DMODEL, 0);

    // 2) u = silu(causal_conv(xs) + conv_b)
    conv_silu_bf<<<dim3((M * DINNER / 8) / 256), blk, 0, stream>>>(
        xs_bf, conv_w, conv_b, u_bf);

    // 3) xdbl = u @ W_x (split-K); reduce also emits x64bf (GEMM4 A, bf16)
    gemm3_splitk<<<dim3(M / 64, KSPLIT), blk, 0, stream>>>(u_bf, W_x, part);
    gemm3_reduce<<<dim3((M * NX / 4 + 255) / 256), blk, 0, stream>>>(part, xdbl, x64bf);

    // 4) GEMM4 (bf16 MFMA, K=64): dl_bf = bf16(softplus(x64 @ W_dt + b_dt))
    castT_bf16<<<dim3(DINNER / 32, DTRANK / 32), blk, 0, stream>>>(
        W_dt, WdtT, DTRANK, DINNER);
    gemm_mfma<2><<<dim3(DINNER / 128, M / 128), blk, 0, stream>>>(
        x64bf, WdtT, nullptr, dl_bf, nullptr, b_dt, M, DINNER, DTRANK, DINNER);

    // 5) chunk-parallel scan
    scan_phase1<<<dim3((B_SZ * DINNER * NCHUNK) / 256), blk, 0, stream>>>(
        dl_bf, u_bf, xdbl, A_log, hend, Sd);
    scan_phase2<<<dim3((B_SZ * DINNER * DSTATE) / 256), blk, 0, stream>>>(
        hend, Sd, A_log);
    scan_phase3<<<dim3((B_SZ * DINNER * NCHUNK) / 256), blk, 0, stream>>>(
        dl_bf, u_bf, zs_bf, xdbl, A_log, Dp, hend, ybf);

    // 5b) W_out^T cast
    castT_bf16<<<dim3(DMODEL / 32, DINNER / 32), blk, 0, stream>>>(
        W_out, WoutT, DINNER, DMODEL);

    // 6) out = y @ W_out  (bf16 MFMA)
    gemm_mfma<0><<<dim3(DMODEL / 128, M / 128), blk, 0, stream>>>(
        ybf, WoutT, out, nullptr, nullptr, nullptr, M, DMODEL, DINNER, DMODEL);
}

// Round 9
// 389.033 us; speedup vs baseline: 1.1340x; 1.0508x over previous
//
#include <hip/hip_runtime.h>
#include <hip/hip_bf16.h>
#include <math.h>

#define B_SZ    2
#define LSEQ    2048
#define DMODEL  1024
#define DINNER  2048
#define DSTATE  16
#define DCONV   4
#define DTRANK  64

#define NCHUNK  64
#define CLEN    (LSEQ / NCHUNK)   // 32

#define KSPLIT  16                // GEMM3 split-K factor (K-chunk = 128)
#define NX      96                // DT_RANK + 2*DSTATE

typedef unsigned short u16;
typedef __bf16 bf16x8 __attribute__((ext_vector_type(8)));
typedef float  f32x4  __attribute__((ext_vector_type(4)));

static __device__ __forceinline__ float sigmoidf_(float x) {
    return 1.0f / (1.0f + __expf(-x));
}
static __device__ __forceinline__ u16 f2b(float f) {   // RNE f32 -> bf16
    unsigned int u = __float_as_uint(f);
    u = (u + 0x7fffu + ((u >> 16) & 1u)) >> 16;
    return (u16)u;
}
static __device__ __forceinline__ float b2f(u16 v) {
    return __uint_as_float(((unsigned int)v) << 16);
}

// ----------------------------------------------------------------------------
// Straight cast f32 -> bf16, 8 elems/thread.
// ----------------------------------------------------------------------------
__global__ __launch_bounds__(256) void cast_bf16(
    const float* __restrict__ in, u16* __restrict__ out, int n8)
{
    const int i = blockIdx.x * 256 + threadIdx.x;
    if (i >= n8) return;
    const float4* p = reinterpret_cast<const float4*>(in + (size_t)i * 8);
    float4 v0 = p[0], v1 = p[1];
    union { u16 u[8]; uint4 q; } r;
    r.u[0] = f2b(v0.x); r.u[1] = f2b(v0.y); r.u[2] = f2b(v0.z); r.u[3] = f2b(v0.w);
    r.u[4] = f2b(v1.x); r.u[5] = f2b(v1.y); r.u[6] = f2b(v1.z); r.u[7] = f2b(v1.w);
    reinterpret_cast<uint4*>(out)[i] = r.q;
}

// ----------------------------------------------------------------------------
// Transpose-cast: in f32 [R][C] -> out bf16 [C][R]. 32x32 LDS tiles.
// ----------------------------------------------------------------------------
__global__ __launch_bounds__(256) void castT_bf16(
    const float* __restrict__ in, u16* __restrict__ out, int R, int C)
{
    __shared__ float t[32][33];
    const int r0 = blockIdx.y * 32, c0 = blockIdx.x * 32;
    const int tr = threadIdx.x >> 3;
    const int tc4 = (threadIdx.x & 7) * 4;
    const float4 v = *reinterpret_cast<const float4*>(in + (size_t)(r0 + tr) * C + c0 + tc4);
    t[tr][tc4 + 0] = v.x; t[tr][tc4 + 1] = v.y; t[tr][tc4 + 2] = v.z; t[tr][tc4 + 3] = v.w;
    __syncthreads();
    union { u16 u[4]; uint2 q; } r;
    #pragma unroll
    for (int j = 0; j < 4; j++) r.u[j] = f2b(t[tc4 + j][tr]);
    *reinterpret_cast<uint2*>(out + (size_t)(c0 + tr) * R + r0 + tc4) = r.q;
}

// ----------------------------------------------------------------------------
// GEMM1: 256x256 tile, BK=64, 8 waves (2x4), double-buffered LDS, prefetch
// distance 2, counted vmcnt(8) at tile boundaries (T3/T4), setprio around
// MFMA clusters (T5), 16B-granule XOR swizzle g^=(row&7) both-sides (T2).
// Epilogue: col<DINNER -> xs=bf16(acc); col>=DINNER -> zs=bf16(silu(acc)).
// Block-uniform split (256-col tiles align with the 2048 boundary).
// ----------------------------------------------------------------------------
__global__ __launch_bounds__(512, 1) void gemm1_8ph(
    const u16* __restrict__ A, const u16* __restrict__ Bt,
    u16* __restrict__ xs_bf, u16* __restrict__ zs_bf)
{
    extern __shared__ u16 smem[];          // [2 matrices][2 bufs][256*64] = 128 KiB
    const int tid  = threadIdx.x;
    const int lane = tid & 63;
    const int wave = tid >> 6;             // 0..7
    const int wr = wave >> 2, wc = wave & 3;
    const int bm = blockIdx.y * 256, bn = blockIdx.x * 256;
    const int lhi = lane >> 4, llo = lane & 15;
    constexpr int K  = DMODEL;             // 1024
    constexpr int NT = K / 64;             // 16 K-tiles

    const int lrow8 = lane >> 3;                         // 0..7: row within 8-row slab
    const int gsrc  = ((lane & 7) ^ lrow8) * 8;          // inverse-swizzled src col (u16)

    f32x4 acc[8][4] = {};

    // stage one 256x64 K-tile of A and B into buffer buf (8 gload_lds per wave)
    auto stage = [&](int kt, int buf) {
        #pragma unroll
        for (int h = 0; h < 2; ++h)
            #pragma unroll
            for (int i = 0; i < 2; ++i) {
                const int rowb = h * 128 + i * 64 + wave * 8;
                const int o16  = buf * 16384 + h * 8192 + i * 4096 + wave * 512;
                const u16* ga = A + (size_t)(bm + rowb + lrow8) * K + kt * 64 + gsrc;
                __builtin_amdgcn_global_load_lds(
                    (const __attribute__((address_space(1))) void*)ga,
                    (__attribute__((address_space(3))) void*)(smem + o16), 16, 0, 0);
                const u16* gb = Bt + (size_t)(bn + rowb + lrow8) * K + kt * 64 + gsrc;
                __builtin_amdgcn_global_load_lds(
                    (const __attribute__((address_space(1))) void*)gb,
                    (__attribute__((address_space(3))) void*)(smem + 32768 + o16), 16, 0, 0);
            }
    };
    // swizzled fragment reads
    auto lda = [&](int m, int ks, int buf) -> bf16x8 {
        const int row = wr * 128 + m * 16 + llo;
        const int g   = (ks * 4 + lhi) ^ (llo & 7);
        return *reinterpret_cast<const bf16x8*>(smem + buf * 16384 + row * 64 + g * 8);
    };
    auto ldb = [&](int n, int ks, int buf) -> bf16x8 {
        const int row = wc * 64 + n * 16 + llo;
        const int g   = (ks * 4 + lhi) ^ (llo & 7);
        return *reinterpret_cast<const bf16x8*>(smem + 32768 + buf * 16384 + row * 64 + g * 8);
    };

    // prologue: tiles 0 and 1 in flight; wait tile 0 (8 newest may remain)
    stage(0, 0);
    stage(1, 1);
    asm volatile("s_waitcnt vmcnt(8)" ::: "memory");
    __builtin_amdgcn_s_barrier();

    #pragma unroll 2
    for (int t = 0; t < NT; ++t) {
        const int cur = t & 1;
        bf16x8 afr[4][2], bf0[2][2], bf1[2][2];

        // P1: A m-half 0 + B n-half 0; MFMA quadrant (m0-3, n0-1)
        #pragma unroll
        for (int m = 0; m < 4; ++m) { afr[m][0] = lda(m, 0, cur); afr[m][1] = lda(m, 1, cur); }
        #pragma unroll
        for (int n = 0; n < 2; ++n) { bf0[n][0] = ldb(n, 0, cur); bf0[n][1] = ldb(n, 1, cur); }
        __builtin_amdgcn_s_setprio(1);
        #pragma unroll
        for (int m = 0; m < 4; ++m)
            #pragma unroll
            for (int n = 0; n < 2; ++n) {
                acc[m][n] = __builtin_amdgcn_mfma_f32_16x16x32_bf16(afr[m][0], bf0[n][0], acc[m][n], 0, 0, 0);
                acc[m][n] = __builtin_amdgcn_mfma_f32_16x16x32_bf16(afr[m][1], bf0[n][1], acc[m][n], 0, 0, 0);
            }
        __builtin_amdgcn_s_setprio(0);

        // P2: B n-half 1; MFMA (m0-3, n2-3)
        #pragma unroll
        for (int n = 0; n < 2; ++n) { bf1[n][0] = ldb(2 + n, 0, cur); bf1[n][1] = ldb(2 + n, 1, cur); }
        __builtin_amdgcn_s_setprio(1);
        #pragma unroll
        for (int m = 0; m < 4; ++m)
            #pragma unroll
            for (int n = 0; n < 2; ++n) {
                acc[m][2 + n] = __builtin_amdgcn_mfma_f32_16x16x32_bf16(afr[m][0], bf1[n][0], acc[m][2 + n], 0, 0, 0);
                acc[m][2 + n] = __builtin_amdgcn_mfma_f32_16x16x32_bf16(afr[m][1], bf1[n][1], acc[m][2 + n], 0, 0, 0);
            }
        __builtin_amdgcn_s_setprio(0);

        // P3: A m-half 1; MFMA (m4-7, n2-3)
        #pragma unroll
        for (int m = 0; m < 4; ++m) { afr[m][0] = lda(4 + m, 0, cur); afr[m][1] = lda(4 + m, 1, cur); }
        __builtin_amdgcn_s_setprio(1);
        #pragma unroll
        for (int m = 0; m < 4; ++m)
            #pragma unroll
            for (int n = 0; n < 2; ++n) {
                acc[4 + m][2 + n] = __builtin_amdgcn_mfma_f32_16x16x32_bf16(afr[m][0], bf1[n][0], acc[4 + m][2 + n], 0, 0, 0);
                acc[4 + m][2 + n] = __builtin_amdgcn_mfma_f32_16x16x32_bf16(afr[m][1], bf1[n][1], acc[4 + m][2 + n], 0, 0, 0);
            }
        __builtin_amdgcn_s_setprio(0);

        // all waves done reading buf[cur] -> safe to overwrite
        __builtin_amdgcn_sched_barrier(0);
        __builtin_amdgcn_s_barrier();
        __builtin_amdgcn_sched_barrier(0);

        // P4: prefetch tile t+2 into buf[cur]; MFMA (m4-7, n0-1)
        if (t + 2 < NT) stage(t + 2, cur);
        __builtin_amdgcn_s_setprio(1);
        #pragma unroll
        for (int m = 0; m < 4; ++m)
            #pragma unroll
            for (int n = 0; n < 2; ++n) {
                acc[4 + m][n] = __builtin_amdgcn_mfma_f32_16x16x32_bf16(afr[m][0], bf0[n][0], acc[4 + m][n], 0, 0, 0);
                acc[4 + m][n] = __builtin_amdgcn_mfma_f32_16x16x32_bf16(afr[m][1], bf0[n][1], acc[4 + m][n], 0, 0, 0);
            }
        __builtin_amdgcn_s_setprio(0);

        // tile boundary: ensure tile t+1 landed for ALL waves (counted vmcnt,
        // never 0 in steady state: t+2's 8 loads stay in flight)
        __builtin_amdgcn_sched_barrier(0);
        if (t + 2 < NT) { asm volatile("s_waitcnt vmcnt(8)" ::: "memory"); }
        else            { asm volatile("s_waitcnt vmcnt(0)" ::: "memory"); }
        __builtin_amdgcn_s_barrier();
        __builtin_amdgcn_sched_barrier(0);
    }

    // epilogue: C/D layout col=lane&15, row=(lane>>4)*4+reg
    const bool is_xs = (bn < DINNER);                // 256-col tiles align with split
    #pragma unroll
    for (int m = 0; m < 8; ++m) {
        const int row0 = bm + wr * 128 + m * 16 + lhi * 4;
        #pragma unroll
        for (int n = 0; n < 4; ++n) {
            const int col = bn + wc * 64 + n * 16 + llo;
            #pragma unroll
            for (int j = 0; j < 4; ++j) {
                float v = acc[m][n][j];
                if (is_xs) {
                    xs_bf[(size_t)(row0 + j) * DINNER + col] = f2b(v);
                } else {
                    v = v * sigmoidf_(v);            // silu(res) pre-gated
                    zs_bf[(size_t)(row0 + j) * DINNER + (col - DINNER)] = f2b(v);
                }
            }
        }
    }
}

// ----------------------------------------------------------------------------
// bf16 MFMA GEMM (m97 structure + swizzle), templated epilogue.
//  EPI 0: C f32 -> Cf (ldc)           [GEMM6]
//  EPI 2: o0 = bf16(softplus(acc + bias[col]))   [GEMM4]
// ----------------------------------------------------------------------------
template<int EPI>
__global__ __launch_bounds__(256) void gemm_mfma(
    const u16* __restrict__ A, const u16* __restrict__ Bt,
    float* __restrict__ Cf, u16* __restrict__ o0, u16* __restrict__ o1,
    const float* __restrict__ bias, int M, int N, int K, int ldc)
{
    __shared__ u16 As[128 * 32];
    __shared__ u16 Bs[128 * 32];
    const int tid  = threadIdx.x;
    const int lane = tid & 63;
    const int wave = tid >> 6;
    const int wr = wave >> 1, wc = wave & 1;
    const int bm = blockIdx.y * 128, bn = blockIdx.x * 128;
    const int lhi = lane >> 4;
    const int llo = lane & 15;

    f32x4 acc[4][4] = {};

    const int rs = (lhi ^ ((llo >> 1) & 3)) * 8;

    for (int k0 = 0; k0 < K; k0 += 32) {
        #pragma unroll
        for (int c = 0; c < 2; ++c) {
            const int s   = c * 256 + wave * 64 + lane;
            const int row = s >> 2, seg = s & 3;
            const int sseg = seg ^ ((row >> 1) & 3);
            const u16* ga = A  + (size_t)(bm + row) * K + k0 + sseg * 8;
            const u16* gb = Bt + (size_t)(bn + row) * K + k0 + sseg * 8;
            __builtin_amdgcn_global_load_lds(
                (const __attribute__((address_space(1))) void*)ga,
                (__attribute__((address_space(3))) void*)(As + (size_t)(c * 256 + wave * 64) * 8),
                16, 0, 0);
            __builtin_amdgcn_global_load_lds(
                (const __attribute__((address_space(1))) void*)gb,
                (__attribute__((address_space(3))) void*)(Bs + (size_t)(c * 256 + wave * 64) * 8),
                16, 0, 0);
        }
        __syncthreads();

        bf16x8 af[4], bfr[4];
        #pragma unroll
        for (int m = 0; m < 4; ++m)
            af[m] = *reinterpret_cast<const bf16x8*>(&As[(wr * 64 + m * 16 + llo) * 32 + rs]);
        #pragma unroll
        for (int n = 0; n < 4; ++n)
            bfr[n] = *reinterpret_cast<const bf16x8*>(&Bs[(wc * 64 + n * 16 + llo) * 32 + rs]);
        #pragma unroll
        for (int m = 0; m < 4; ++m)
            #pragma unroll
            for (int n = 0; n < 4; ++n)
                acc[m][n] = __builtin_amdgcn_mfma_f32_16x16x32_bf16(af[m], bfr[n], acc[m][n], 0, 0, 0);
        __syncthreads();
    }

    #pragma unroll
    for (int m = 0; m < 4; ++m) {
        const int row0 = bm + wr * 64 + m * 16 + lhi * 4;
        #pragma unroll
        for (int n = 0; n < 4; ++n) {
            const int col = bn + wc * 64 + n * 16 + llo;
            #pragma unroll
            for (int j = 0; j < 4; ++j) {
                float v = acc[m][n][j];
                if (EPI == 0) {
                    Cf[(size_t)(row0 + j) * ldc + col] = v;
                } else {
                    v += bias[col];
                    v = (v > 20.f) ? v : log1pf(__expf(v));   // softplus
                    o0[(size_t)(row0 + j) * ldc + col] = f2b(v);
                }
            }
        }
    }
}

// ----------------------------------------------------------------------------
// Causal depthwise conv (width 4, left pad 3) + bias + SiLU. bf16 in/out.
// ----------------------------------------------------------------------------
__global__ __launch_bounds__(256) void conv_silu_bf(
    const u16* __restrict__ xs, const float* __restrict__ conv_w,
    const float* __restrict__ conv_b, u16* __restrict__ u)
{
    const int g  = blockIdx.x * 256 + threadIdx.x;     // over (bl, d/8)
    const int d8 = (g & 255) * 8;
    const int bl = g >> 8;
    const int l  = bl & (LSEQ - 1);

    float4 wv[8];
    #pragma unroll
    for (int j = 0; j < 8; j++)
        wv[j] = *reinterpret_cast<const float4*>(conv_w + (size_t)(d8 + j) * DCONV);

    float acc[8];
    #pragma unroll
    for (int j = 0; j < 8; j++) acc[j] = conv_b[d8 + j];

    #pragma unroll
    for (int k = 0; k < DCONV; k++) {
        const int l2 = l - (DCONV - 1) + k;
        if (l2 < 0) continue;
        const uint4 q = *reinterpret_cast<const uint4*>(
            xs + (size_t)(bl - (DCONV - 1) + k) * DINNER + d8);
        const u16* e = reinterpret_cast<const u16*>(&q);
        #pragma unroll
        for (int j = 0; j < 8; j++) {
            const float w = (k == 0) ? wv[j].x : (k == 1) ? wv[j].y : (k == 2) ? wv[j].z : wv[j].w;
            acc[j] = fmaf(b2f(e[j]), w, acc[j]);
        }
    }
    union { u16 u[8]; uint4 q; } r;
    #pragma unroll
    for (int j = 0; j < 8; j++) {
        const float v = acc[j];
        r.u[j] = f2b(v * sigmoidf_(v));
    }
    *reinterpret_cast<uint4*>(u + (size_t)bl * DINNER + d8) = r.q;
}

// ----------------------------------------------------------------------------
// GEMM3 split-K: partial[s][M][96] = u[M, ks] @ W_x[ks, :96], u is bf16.
// ----------------------------------------------------------------------------
__global__ __launch_bounds__(256) void gemm3_splitk(
    const u16* __restrict__ ubf, const float* __restrict__ Wx,
    float* __restrict__ partial)
{
    __shared__ float us[64][65];
    __shared__ float wsm[64][96];

    const int tid = threadIdx.x;
    const int r0 = blockIdx.x * 64;
    const int k0 = blockIdx.y * (DINNER / KSPLIT);

    const int orow = tid >> 2;
    const int oc0  = (tid & 3) * 24;

    float acc[24];
    #pragma unroll
    for (int j = 0; j < 24; j++) acc[j] = 0.f;

    for (int ks = 0; ks < DINNER / KSPLIT; ks += 64) {
        {
            const int row = tid >> 2;
            const int c16 = (tid & 3) << 4;
            const uint4* src = reinterpret_cast<const uint4*>(
                ubf + (size_t)(r0 + row) * DINNER + k0 + ks + c16);
            const uint4 q0 = src[0], q1 = src[1];
            const u16* e0 = reinterpret_cast<const u16*>(&q0);
            const u16* e1 = reinterpret_cast<const u16*>(&q1);
            #pragma unroll
            for (int j = 0; j < 8; j++) us[row][c16 + j]     = b2f(e0[j]);
            #pragma unroll
            for (int j = 0; j < 8; j++) us[row][c16 + 8 + j] = b2f(e1[j]);
        }
        #pragma unroll
        for (int j = 0; j < 6; j++) {
            const int fid = tid + j * 256;
            const int kr  = fid / 24;
            const int c4  = (fid % 24) * 4;
            *reinterpret_cast<float4*>(&wsm[kr][c4]) =
                *reinterpret_cast<const float4*>(Wx + (size_t)(k0 + ks + kr) * NX + c4);
        }
        __syncthreads();

        for (int kk = 0; kk < 64; ++kk) {
            const float uv = us[orow][kk];
            #pragma unroll
            for (int j = 0; j < 24; j++)
                acc[j] = fmaf(uv, wsm[kk][oc0 + j], acc[j]);
        }
        __syncthreads();
    }

    float* pp = partial + ((size_t)blockIdx.y * (B_SZ * LSEQ) + r0 + orow) * NX + oc0;
    #pragma unroll
    for (int j = 0; j < 24; j += 4)
        *reinterpret_cast<float4*>(pp + j) = make_float4(acc[j], acc[j+1], acc[j+2], acc[j+3]);
}

// reduce partials -> xdbl f32 [M][96]; also emit bf16 copy of cols 0..63 (GEMM4 A)
__global__ __launch_bounds__(256) void gemm3_reduce(
    const float* __restrict__ partial, float* __restrict__ xdbl,
    u16* __restrict__ x64bf)
{
    const int i = blockIdx.x * 256 + threadIdx.x;   // float4 index over [M][96]
    if (i >= B_SZ * LSEQ * NX / 4) return;
    float4 s = make_float4(0.f, 0.f, 0.f, 0.f);
    #pragma unroll
    for (int p = 0; p < KSPLIT; p++) {
        const float4 v = reinterpret_cast<const float4*>(
            partial + (size_t)p * (B_SZ * LSEQ) * NX)[i];
        s.x += v.x; s.y += v.y; s.z += v.z; s.w += v.w;
    }
    reinterpret_cast<float4*>(xdbl)[i] = s;

    const int col4 = (i % 24) * 4;
    if (col4 < DTRANK) {
        const int row = i / 24;
        union { u16 u[4]; uint2 q; } r;
        r.u[0] = f2b(s.x); r.u[1] = f2b(s.y); r.u[2] = f2b(s.z); r.u[3] = f2b(s.w);
        *reinterpret_cast<uint2*>(x64bf + (size_t)row * DTRANK + col4) = r.q;
    }
}

// ----------------------------------------------------------------------------
// Chunk-parallel selective scan (3 phases). delta comes in as bf16 (dl_bf).
// ----------------------------------------------------------------------------
__global__ __launch_bounds__(256) void scan_phase1(
    const u16* __restrict__ dl_bf, const u16* __restrict__ ubf,
    const float* __restrict__ xdbl, const float* __restrict__ A_log,
    float* __restrict__ hend, float* __restrict__ Sd)
{
    const int idx = blockIdx.x * 256 + threadIdx.x;   // ((b*NCHUNK+c)*DINNER+d)
    const int d = idx & (DINNER - 1);
    const int c = (idx >> 11) & (NCHUNK - 1);
    const int b = idx >> 17;

    float a[DSTATE];
    #pragma unroll
    for (int n = 0; n < DSTATE; n++) a[n] = -__expf(A_log[d * DSTATE + n]);

    float h[DSTATE];
    #pragma unroll
    for (int n = 0; n < DSTATE; n++) h[n] = 0.f;
    float sd = 0.f;

    const int l0 = b * LSEQ + c * CLEN;
    for (int i = 0; i < CLEN; ++i) {
        const size_t r = (size_t)(l0 + i);
        const float dv = b2f(dl_bf[r * DINNER + d]);
        const float uv = b2f(ubf[r * DINNER + d]);
        sd += dv;
        float Bv[DSTATE];
        {
            const float4* bp = reinterpret_cast<const float4*>(xdbl + r * NX + DTRANK);
            float4 q;
            q = bp[0]; Bv[0]=q.x;  Bv[1]=q.y;  Bv[2]=q.z;  Bv[3]=q.w;
            q = bp[1]; Bv[4]=q.x;  Bv[5]=q.y;  Bv[6]=q.z;  Bv[7]=q.w;
            q = bp[2]; Bv[8]=q.x;  Bv[9]=q.y;  Bv[10]=q.z; Bv[11]=q.w;
            q = bp[3]; Bv[12]=q.x; Bv[13]=q.y; Bv[14]=q.z; Bv[15]=q.w;
        }
        const float du = dv * uv;
        #pragma unroll
        for (int n = 0; n < DSTATE; n++)
            h[n] = fmaf(__expf(dv * a[n]), h[n], du * Bv[n]);
    }

    float* hp = hend + ((size_t)(b * DINNER + d) * NCHUNK + c) * DSTATE;
    #pragma unroll
    for (int n = 0; n < DSTATE; n += 4)
        *reinterpret_cast<float4*>(hp + n) = make_float4(h[n], h[n+1], h[n+2], h[n+3]);
    Sd[(size_t)(b * DINNER + d) * NCHUNK + c] = sd;
}

__global__ __launch_bounds__(256) void scan_phase2(
    float* __restrict__ hend, const float* __restrict__ Sd,
    const float* __restrict__ A_log)
{
    const int idx = blockIdx.x * 256 + threadIdx.x;
    if (idx >= B_SZ * DINNER * DSTATE) return;
    const int n = idx & (DSTATE - 1);
    const int d = (idx >> 4) & (DINNER - 1);
    const int b = idx >> 15;

    const float an = -__expf(A_log[d * DSTATE + n]);
    const size_t base = (size_t)(b * DINNER + d) * NCHUNK;
    float carry = 0.f;
    for (int c = 0; c < NCHUNK; ++c) {
        const float P = __expf(an * Sd[base + c]);
        const size_t off = (base + c) * DSTATE + n;
        const float tmp = hend[off];
        hend[off] = carry;
        carry = fmaf(P, carry, tmp);
    }
}

__global__ __launch_bounds__(256) void scan_phase3(
    const u16* __restrict__ dl_bf, const u16* __restrict__ ubf,
    const u16* __restrict__ zs_bf, const float* __restrict__ xdbl,
    const float* __restrict__ A_log, const float* __restrict__ Dp,
    const float* __restrict__ hin, u16* __restrict__ ybf)
{
    const int idx = blockIdx.x * 256 + threadIdx.x;
    const int d = idx & (DINNER - 1);
    const int c = (idx >> 11) & (NCHUNK - 1);
    const int b = idx >> 17;

    float a[DSTATE];
    #pragma unroll
    for (int n = 0; n < DSTATE; n++) a[n] = -__expf(A_log[d * DSTATE + n]);
    const float Dd = Dp[d];

    float h[DSTATE];
    {
        const float* hp = hin + ((size_t)(b * DINNER + d) * NCHUNK + c) * DSTATE;
        #pragma unroll
        for (int n = 0; n < DSTATE; n += 4) {
            const float4 t = *reinterpret_cast<const float4*>(hp + n);
            h[n] = t.x; h[n+1] = t.y; h[n+2] = t.z; h[n+3] = t.w;
        }
    }

    const int l0 = b * LSEQ + c * CLEN;
    for (int i = 0; i < CLEN; ++i) {
        const size_t r = (size_t)(l0 + i);
        const float dv = b2f(dl_bf[r * DINNER + d]);
        const float uv = b2f(ubf[r * DINNER + d]);

        const float4* bp = reinterpret_cast<const float4*>(xdbl + r * NX + DTRANK);
        float Bv[DSTATE], Cv[DSTATE];
        {
            float4 t;
            t = bp[0]; Bv[0]=t.x;  Bv[1]=t.y;  Bv[2]=t.z;  Bv[3]=t.w;
            t = bp[1]; Bv[4]=t.x;  Bv[5]=t.y;  Bv[6]=t.z;  Bv[7]=t.w;
            t = bp[2]; Bv[8]=t.x;  Bv[9]=t.y;  Bv[10]=t.z; Bv[11]=t.w;
            t = bp[3]; Bv[12]=t.x; Bv[13]=t.y; Bv[14]=t.z; Bv[15]=t.w;
            t = bp[4]; Cv[0]=t.x;  Cv[1]=t.y;  Cv[2]=t.z;  Cv[3]=t.w;
            t = bp[5]; Cv[4]=t.x;  Cv[5]=t.y;  Cv[6]=t.z;  Cv[7]=t.w;
            t = bp[6]; Cv[8]=t.x;  Cv[9]=t.y;  Cv[10]=t.z; Cv[11]=t.w;
            t = bp[7]; Cv[12]=t.x; Cv[13]=t.y; Cv[14]=t.z; Cv[15]=t.w;
        }

        const float du = dv * uv;
        float yv = 0.f;
        #pragma unroll
        for (int n = 0; n < DSTATE; n++) {
            h[n] = fmaf(__expf(dv * a[n]), h[n], du * Bv[n]);
            yv = fmaf(h[n], Cv[n], yv);
        }
        yv = fmaf(uv, Dd, yv);

        const float g = b2f(zs_bf[r * DINNER + d]);   // pre-gated silu(res)
        ybf[r * DINNER + d] = f2b(yv * g);
    }
}

// ----------------------------------------------------------------------------
extern "C" void kernel_launch(void* const* d_in, const int* in_sizes, int n_in,
                              void* d_out, int out_size, void* d_ws, size_t ws_size,
                              hipStream_t stream) {
    const float* x      = (const float*)d_in[0];
    const float* W_in   = (const float*)d_in[1];
    const float* conv_w = (const float*)d_in[2];
    const float* conv_b = (const float*)d_in[3];
    const float* W_x    = (const float*)d_in[4];
    const float* W_dt   = (const float*)d_in[5];
    const float* b_dt   = (const float*)d_in[6];
    const float* A_log  = (const float*)d_in[7];
    const float* Dp     = (const float*)d_in[8];
    const float* W_out  = (const float*)d_in[9];
    float* out = (float*)d_out;

    const int M = B_SZ * LSEQ;   // 4096

    // workspace layout (~134 MB)
    float* ws     = (float*)d_ws;
    float* xdbl   = ws;                                           // [4096,96] f32
    float* hend   = xdbl + (size_t)M * NX;                        // [2,2048,64,16] f32
    float* Sd     = hend + (size_t)B_SZ * DINNER * NCHUNK * DSTATE;
    float* part   = Sd   + (size_t)B_SZ * DINNER * NCHUNK;        // [16,4096,96] f32
    u16*   xs_bf  = (u16*)(part + (size_t)KSPLIT * M * NX);       // [4096,2048] bf16
    u16*   zs_bf  = xs_bf + (size_t)M * DINNER;                   // [4096,2048] bf16
    u16*   u_bf   = zs_bf + (size_t)M * DINNER;                   // [4096,2048] bf16
    u16*   dl_bf  = u_bf  + (size_t)M * DINNER;                   // [4096,2048] bf16
    u16*   xbf    = dl_bf + (size_t)M * DINNER;                   // [4096,1024] bf16
    u16*   WinT   = xbf   + (size_t)M * DMODEL;                   // [4096,1024] bf16
    u16*   WoutT  = WinT  + (size_t)M * DMODEL;                   // [1024,2048] bf16
    u16*   x64bf  = WoutT + (size_t)DMODEL * DINNER;              // [4096,64] bf16
    u16*   WdtT   = x64bf + (size_t)M * DTRANK;                   // [2048,64] bf16
    u16*   ybf    = xbf;                                          // aliases xbf+WinT

    dim3 blk(256);

    // 0) casts for GEMM1
    cast_bf16<<<dim3((M * DMODEL / 8) / 256), blk, 0, stream>>>(x, xbf, M * DMODEL / 8);
    castT_bf16<<<dim3((2 * DINNER) / 32, DMODEL / 32), blk, 0, stream>>>(
        W_in, WinT, DMODEL, 2 * DINNER);

    // 1) GEMM1 (256² pipelined): xs_bf + pre-gated zs_bf, both bf16
    gemm1_8ph<<<dim3((2 * DINNER) / 256, M / 256), dim3(512), 131072, stream>>>(
        xbf, WinT, xs_bf, zs_bf);

    // 2) u = silu(causal_conv(xs) + conv_b)
    conv_silu_bf<<<dim3((M * DINNER / 8) / 256), blk, 0, stream>>>(
        xs_bf, conv_w, conv_b, u_bf);

    // 3) xdbl = u @ W_x (split-K); reduce also emits x64bf (GEMM4 A, bf16)
    gemm3_splitk<<<dim3(M / 64, KSPLIT), blk, 0, stream>>>(u_bf, W_x, part);
    gemm3_reduce<<<dim3((M * NX / 4 + 255) / 256), blk, 0, stream>>>(part, xdbl, x64bf);

    // 4) GEMM4 (bf16 MFMA, K=64): dl_bf = bf16(softplus(x64 @ W_dt + b_dt))
    castT_bf16<<<dim3(DINNER / 32, DTRANK / 32), blk, 0, stream>>>(
        W_dt, WdtT, DTRANK, DINNER);
    gemm_mfma<2><<<dim3(DINNER / 128, M / 128), blk, 0, stream>>>(
        x64bf, WdtT, nullptr, dl_bf, nullptr, b_dt, M, DINNER, DTRANK, DINNER);

    // 5) chunk-parallel scan
    scan_phase1<<<dim3((B_SZ * DINNER * NCHUNK) / 256), blk, 0, stream>>>(
        dl_bf, u_bf, xdbl, A_log, hend, Sd);
    scan_phase2<<<dim3((B_SZ * DINNER * DSTATE) / 256), blk, 0, stream>>>(
        hend, Sd, A_log);
    scan_phase3<<<dim3((B_SZ * DINNER * NCHUNK) / 256), blk, 0, stream>>>(
        dl_bf, u_bf, zs_bf, xdbl, A_log, Dp, hend, ybf);

    // 5b) W_out^T cast
    castT_bf16<<<dim3(DMODEL / 32, DINNER / 32), blk, 0, stream>>>(
        W_out, WoutT, DINNER, DMODEL);

    // 6) out = y @ W_out  (bf16 MFMA)
    gemm_mfma<0><<<dim3(DMODEL / 128, M / 128), blk, 0, stream>>>(
        ybf, WoutT, out, nullptr, nullptr, nullptr, M, DMODEL, DINNER, DMODEL);
}

// Round 10
// 387.349 us; speedup vs baseline: 1.1389x; 1.0043x over previous
//
#include <hip/hip_runtime.h>
#include <hip/hip_bf16.h>
#include <math.h>

#define B_SZ    2
#define LSEQ    2048
#define DMODEL  1024
#define DINNER  2048
#define DSTATE  16
#define DCONV   4
#define DTRANK  64

#define NCHUNK  64
#define CLEN    (LSEQ / NCHUNK)   // 32

#define KSPLIT  8                 // GEMM3 split-K factor (K-chunk = 256)
#define NX      96                // DT_RANK + 2*DSTATE

typedef unsigned short u16;
typedef __bf16 bf16x8 __attribute__((ext_vector_type(8)));
typedef float  f32x4  __attribute__((ext_vector_type(4)));

static __device__ __forceinline__ float sigmoidf_(float x) {
    return 1.0f / (1.0f + __expf(-x));
}
static __device__ __forceinline__ u16 f2b(float f) {   // RNE f32 -> bf16
    unsigned int u = __float_as_uint(f);
    u = (u + 0x7fffu + ((u >> 16) & 1u)) >> 16;
    return (u16)u;
}
static __device__ __forceinline__ float b2f(u16 v) {
    return __uint_as_float(((unsigned int)v) << 16);
}

// Bijective XCD-chunked block swizzle (T1, m204): requires nwg % 8 == 0.
// Consecutive logical tiles land on the SAME XCD -> A-panel / B-panel L2 reuse.
static __device__ __forceinline__ void xcd_swizzle(int& bx, int& by) {
    const int gx  = gridDim.x;
    const int lin = by * gx + bx;                  // HW dispatch order (x fastest)
    const int cpx = (gx * gridDim.y) >> 3;         // chunks per XCD
    const int wg  = (lin & 7) * cpx + (lin >> 3);  // logical tile id
    bx = wg % gx;  by = wg / gx;
}

// ----------------------------------------------------------------------------
// Straight cast f32 -> bf16, 8 elems/thread.
// ----------------------------------------------------------------------------
__global__ __launch_bounds__(256) void cast_bf16(
    const float* __restrict__ in, u16* __restrict__ out, int n8)
{
    const int i = blockIdx.x * 256 + threadIdx.x;
    if (i >= n8) return;
    const float4* p = reinterpret_cast<const float4*>(in + (size_t)i * 8);
    float4 v0 = p[0], v1 = p[1];
    union { u16 u[8]; uint4 q; } r;
    r.u[0] = f2b(v0.x); r.u[1] = f2b(v0.y); r.u[2] = f2b(v0.z); r.u[3] = f2b(v0.w);
    r.u[4] = f2b(v1.x); r.u[5] = f2b(v1.y); r.u[6] = f2b(v1.z); r.u[7] = f2b(v1.w);
    reinterpret_cast<uint4*>(out)[i] = r.q;
}

// ----------------------------------------------------------------------------
// Transpose-cast: in f32 [R][C] -> out bf16 [C][R]. 32x32 LDS tiles.
// ----------------------------------------------------------------------------
__global__ __launch_bounds__(256) void castT_bf16(
    const float* __restrict__ in, u16* __restrict__ out, int R, int C)
{
    __shared__ float t[32][33];
    const int r0 = blockIdx.y * 32, c0 = blockIdx.x * 32;
    const int tr = threadIdx.x >> 3;
    const int tc4 = (threadIdx.x & 7) * 4;
    const float4 v = *reinterpret_cast<const float4*>(in + (size_t)(r0 + tr) * C + c0 + tc4);
    t[tr][tc4 + 0] = v.x; t[tr][tc4 + 1] = v.y; t[tr][tc4 + 2] = v.z; t[tr][tc4 + 3] = v.w;
    __syncthreads();
    union { u16 u[4]; uint2 q; } r;
    #pragma unroll
    for (int j = 0; j < 4; j++) r.u[j] = f2b(t[tc4 + j][tr]);
    *reinterpret_cast<uint2*>(out + (size_t)(c0 + tr) * R + r0 + tc4) = r.q;
}

// ----------------------------------------------------------------------------
// GEMM1: 256x256 tile, BK=64, 8 waves (2x4), double-buffered LDS, prefetch
// distance 2, counted vmcnt(8) (T3/T4), setprio (T5), XOR swizzle (T2),
// XCD-chunked block swizzle (T1).
// ----------------------------------------------------------------------------
__global__ __launch_bounds__(512, 1) void gemm1_8ph(
    const u16* __restrict__ A, const u16* __restrict__ Bt,
    u16* __restrict__ xs_bf, u16* __restrict__ zs_bf)
{
    extern __shared__ u16 smem[];          // [2 matrices][2 bufs][256*64] = 128 KiB
    const int tid  = threadIdx.x;
    const int lane = tid & 63;
    const int wave = tid >> 6;             // 0..7
    const int wr = wave >> 2, wc = wave & 3;
    int bxs = blockIdx.x, bys = blockIdx.y;
    xcd_swizzle(bxs, bys);
    const int bm = bys * 256, bn = bxs * 256;
    const int lhi = lane >> 4, llo = lane & 15;
    constexpr int K  = DMODEL;             // 1024
    constexpr int NT = K / 64;             // 16 K-tiles

    const int lrow8 = lane >> 3;                         // 0..7: row within 8-row slab
    const int gsrc  = ((lane & 7) ^ lrow8) * 8;          // inverse-swizzled src col (u16)

    f32x4 acc[8][4] = {};

    // stage one 256x64 K-tile of A and B into buffer buf (8 gload_lds per wave)
    auto stage = [&](int kt, int buf) {
        #pragma unroll
        for (int h = 0; h < 2; ++h)
            #pragma unroll
            for (int i = 0; i < 2; ++i) {
                const int rowb = h * 128 + i * 64 + wave * 8;
                const int o16  = buf * 16384 + h * 8192 + i * 4096 + wave * 512;
                const u16* ga = A + (size_t)(bm + rowb + lrow8) * K + kt * 64 + gsrc;
                __builtin_amdgcn_global_load_lds(
                    (const __attribute__((address_space(1))) void*)ga,
                    (__attribute__((address_space(3))) void*)(smem + o16), 16, 0, 0);
                const u16* gb = Bt + (size_t)(bn + rowb + lrow8) * K + kt * 64 + gsrc;
                __builtin_amdgcn_global_load_lds(
                    (const __attribute__((address_space(1))) void*)gb,
                    (__attribute__((address_space(3))) void*)(smem + 32768 + o16), 16, 0, 0);
            }
    };
    // swizzled fragment reads
    auto lda = [&](int m, int ks, int buf) -> bf16x8 {
        const int row = wr * 128 + m * 16 + llo;
        const int g   = (ks * 4 + lhi) ^ (llo & 7);
        return *reinterpret_cast<const bf16x8*>(smem + buf * 16384 + row * 64 + g * 8);
    };
    auto ldb = [&](int n, int ks, int buf) -> bf16x8 {
        const int row = wc * 64 + n * 16 + llo;
        const int g   = (ks * 4 + lhi) ^ (llo & 7);
        return *reinterpret_cast<const bf16x8*>(smem + 32768 + buf * 16384 + row * 64 + g * 8);
    };

    // prologue: tiles 0 and 1 in flight; wait tile 0 (8 newest may remain)
    stage(0, 0);
    stage(1, 1);
    asm volatile("s_waitcnt vmcnt(8)" ::: "memory");
    __builtin_amdgcn_s_barrier();

    #pragma unroll 2
    for (int t = 0; t < NT; ++t) {
        const int cur = t & 1;
        bf16x8 afr[4][2], bf0[2][2], bf1[2][2];

        // P1: A m-half 0 + B n-half 0; MFMA quadrant (m0-3, n0-1)
        #pragma unroll
        for (int m = 0; m < 4; ++m) { afr[m][0] = lda(m, 0, cur); afr[m][1] = lda(m, 1, cur); }
        #pragma unroll
        for (int n = 0; n < 2; ++n) { bf0[n][0] = ldb(n, 0, cur); bf0[n][1] = ldb(n, 1, cur); }
        __builtin_amdgcn_s_setprio(1);
        #pragma unroll
        for (int m = 0; m < 4; ++m)
            #pragma unroll
            for (int n = 0; n < 2; ++n) {
                acc[m][n] = __builtin_amdgcn_mfma_f32_16x16x32_bf16(afr[m][0], bf0[n][0], acc[m][n], 0, 0, 0);
                acc[m][n] = __builtin_amdgcn_mfma_f32_16x16x32_bf16(afr[m][1], bf0[n][1], acc[m][n], 0, 0, 0);
            }
        __builtin_amdgcn_s_setprio(0);

        // P2: B n-half 1; MFMA (m0-3, n2-3)
        #pragma unroll
        for (int n = 0; n < 2; ++n) { bf1[n][0] = ldb(2 + n, 0, cur); bf1[n][1] = ldb(2 + n, 1, cur); }
        __builtin_amdgcn_s_setprio(1);
        #pragma unroll
        for (int m = 0; m < 4; ++m)
            #pragma unroll
            for (int n = 0; n < 2; ++n) {
                acc[m][2 + n] = __builtin_amdgcn_mfma_f32_16x16x32_bf16(afr[m][0], bf1[n][0], acc[m][2 + n], 0, 0, 0);
                acc[m][2 + n] = __builtin_amdgcn_mfma_f32_16x16x32_bf16(afr[m][1], bf1[n][1], acc[m][2 + n], 0, 0, 0);
            }
        __builtin_amdgcn_s_setprio(0);

        // P3: A m-half 1; MFMA (m4-7, n2-3)
        #pragma unroll
        for (int m = 0; m < 4; ++m) { afr[m][0] = lda(4 + m, 0, cur); afr[m][1] = lda(4 + m, 1, cur); }
        __builtin_amdgcn_s_setprio(1);
        #pragma unroll
        for (int m = 0; m < 4; ++m)
            #pragma unroll
            for (int n = 0; n < 2; ++n) {
                acc[4 + m][2 + n] = __builtin_amdgcn_mfma_f32_16x16x32_bf16(afr[m][0], bf1[n][0], acc[4 + m][2 + n], 0, 0, 0);
                acc[4 + m][2 + n] = __builtin_amdgcn_mfma_f32_16x16x32_bf16(afr[m][1], bf1[n][1], acc[4 + m][2 + n], 0, 0, 0);
            }
        __builtin_amdgcn_s_setprio(0);

        // all waves done reading buf[cur] -> safe to overwrite
        __builtin_amdgcn_sched_barrier(0);
        __builtin_amdgcn_s_barrier();
        __builtin_amdgcn_sched_barrier(0);

        // P4: prefetch tile t+2 into buf[cur]; MFMA (m4-7, n0-1)
        if (t + 2 < NT) stage(t + 2, cur);
        __builtin_amdgcn_s_setprio(1);
        #pragma unroll
        for (int m = 0; m < 4; ++m)
            #pragma unroll
            for (int n = 0; n < 2; ++n) {
                acc[4 + m][n] = __builtin_amdgcn_mfma_f32_16x16x32_bf16(afr[m][0], bf0[n][0], acc[4 + m][n], 0, 0, 0);
                acc[4 + m][n] = __builtin_amdgcn_mfma_f32_16x16x32_bf16(afr[m][1], bf0[n][1], acc[4 + m][n], 0, 0, 0);
            }
        __builtin_amdgcn_s_setprio(0);

        // tile boundary: ensure tile t+1 landed for ALL waves (counted vmcnt,
        // never 0 in steady state: t+2's 8 loads stay in flight)
        __builtin_amdgcn_sched_barrier(0);
        if (t + 2 < NT) { asm volatile("s_waitcnt vmcnt(8)" ::: "memory"); }
        else            { asm volatile("s_waitcnt vmcnt(0)" ::: "memory"); }
        __builtin_amdgcn_s_barrier();
        __builtin_amdgcn_sched_barrier(0);
    }

    // epilogue: C/D layout col=lane&15, row=(lane>>4)*4+reg
    const bool is_xs = (bn < DINNER);                // 256-col tiles align with split
    #pragma unroll
    for (int m = 0; m < 8; ++m) {
        const int row0 = bm + wr * 128 + m * 16 + lhi * 4;
        #pragma unroll
        for (int n = 0; n < 4; ++n) {
            const int col = bn + wc * 64 + n * 16 + llo;
            #pragma unroll
            for (int j = 0; j < 4; ++j) {
                float v = acc[m][n][j];
                if (is_xs) {
                    xs_bf[(size_t)(row0 + j) * DINNER + col] = f2b(v);
                } else {
                    v = v * sigmoidf_(v);            // silu(res) pre-gated
                    zs_bf[(size_t)(row0 + j) * DINNER + (col - DINNER)] = f2b(v);
                }
            }
        }
    }
}

// ----------------------------------------------------------------------------
// bf16 MFMA GEMM (m97 structure + T2 swizzle + T1 block swizzle).
//  EPI 0: C f32 -> Cf (ldc)                       [GEMM6]
//  EPI 2: o0 = bf16(softplus(acc + bias[col]))    [GEMM4]
// ----------------------------------------------------------------------------
template<int EPI>
__global__ __launch_bounds__(256) void gemm_mfma(
    const u16* __restrict__ A, const u16* __restrict__ Bt,
    float* __restrict__ Cf, u16* __restrict__ o0, u16* __restrict__ o1,
    const float* __restrict__ bias, int M, int N, int K, int ldc)
{
    __shared__ u16 As[128 * 32];
    __shared__ u16 Bs[128 * 32];
    const int tid  = threadIdx.x;
    const int lane = tid & 63;
    const int wave = tid >> 6;
    const int wr = wave >> 1, wc = wave & 1;
    int bxs = blockIdx.x, bys = blockIdx.y;
    xcd_swizzle(bxs, bys);
    const int bm = bys * 128, bn = bxs * 128;
    const int lhi = lane >> 4;
    const int llo = lane & 15;

    f32x4 acc[4][4] = {};

    const int rs = (lhi ^ ((llo >> 1) & 3)) * 8;

    for (int k0 = 0; k0 < K; k0 += 32) {
        #pragma unroll
        for (int c = 0; c < 2; ++c) {
            const int s   = c * 256 + wave * 64 + lane;
            const int row = s >> 2, seg = s & 3;
            const int sseg = seg ^ ((row >> 1) & 3);
            const u16* ga = A  + (size_t)(bm + row) * K + k0 + sseg * 8;
            const u16* gb = Bt + (size_t)(bn + row) * K + k0 + sseg * 8;
            __builtin_amdgcn_global_load_lds(
                (const __attribute__((address_space(1))) void*)ga,
                (__attribute__((address_space(3))) void*)(As + (size_t)(c * 256 + wave * 64) * 8),
                16, 0, 0);
            __builtin_amdgcn_global_load_lds(
                (const __attribute__((address_space(1))) void*)gb,
                (__attribute__((address_space(3))) void*)(Bs + (size_t)(c * 256 + wave * 64) * 8),
                16, 0, 0);
        }
        __syncthreads();

        bf16x8 af[4], bfr[4];
        #pragma unroll
        for (int m = 0; m < 4; ++m)
            af[m] = *reinterpret_cast<const bf16x8*>(&As[(wr * 64 + m * 16 + llo) * 32 + rs]);
        #pragma unroll
        for (int n = 0; n < 4; ++n)
            bfr[n] = *reinterpret_cast<const bf16x8*>(&Bs[(wc * 64 + n * 16 + llo) * 32 + rs]);
        #pragma unroll
        for (int m = 0; m < 4; ++m)
            #pragma unroll
            for (int n = 0; n < 4; ++n)
                acc[m][n] = __builtin_amdgcn_mfma_f32_16x16x32_bf16(af[m], bfr[n], acc[m][n], 0, 0, 0);
        __syncthreads();
    }

    #pragma unroll
    for (int m = 0; m < 4; ++m) {
        const int row0 = bm + wr * 64 + m * 16 + lhi * 4;
        #pragma unroll
        for (int n = 0; n < 4; ++n) {
            const int col = bn + wc * 64 + n * 16 + llo;
            #pragma unroll
            for (int j = 0; j < 4; ++j) {
                float v = acc[m][n][j];
                if (EPI == 0) {
                    Cf[(size_t)(row0 + j) * ldc + col] = v;
                } else {
                    v += bias[col];
                    v = (v > 20.f) ? v : log1pf(__expf(v));   // softplus
                    o0[(size_t)(row0 + j) * ldc + col] = f2b(v);
                }
            }
        }
    }
}

// ----------------------------------------------------------------------------
// Causal depthwise conv (width 4, left pad 3) + bias + SiLU. bf16 in/out.
// ----------------------------------------------------------------------------
__global__ __launch_bounds__(256) void conv_silu_bf(
    const u16* __restrict__ xs, const float* __restrict__ conv_w,
    const float* __restrict__ conv_b, u16* __restrict__ u)
{
    const int g  = blockIdx.x * 256 + threadIdx.x;     // over (bl, d/8)
    const int d8 = (g & 255) * 8;
    const int bl = g >> 8;
    const int l  = bl & (LSEQ - 1);

    float4 wv[8];
    #pragma unroll
    for (int j = 0; j < 8; j++)
        wv[j] = *reinterpret_cast<const float4*>(conv_w + (size_t)(d8 + j) * DCONV);

    float acc[8];
    #pragma unroll
    for (int j = 0; j < 8; j++) acc[j] = conv_b[d8 + j];

    #pragma unroll
    for (int k = 0; k < DCONV; k++) {
        const int l2 = l - (DCONV - 1) + k;
        if (l2 < 0) continue;
        const uint4 q = *reinterpret_cast<const uint4*>(
            xs + (size_t)(bl - (DCONV - 1) + k) * DINNER + d8);
        const u16* e = reinterpret_cast<const u16*>(&q);
        #pragma unroll
        for (int j = 0; j < 8; j++) {
            const float w = (k == 0) ? wv[j].x : (k == 1) ? wv[j].y : (k == 2) ? wv[j].z : wv[j].w;
            acc[j] = fmaf(b2f(e[j]), w, acc[j]);
        }
    }
    union { u16 u[8]; uint4 q; } r;
    #pragma unroll
    for (int j = 0; j < 8; j++) {
        const float v = acc[j];
        r.u[j] = f2b(v * sigmoidf_(v));
    }
    *reinterpret_cast<uint4*>(u + (size_t)bl * DINNER + d8) = r.q;
}

// ----------------------------------------------------------------------------
// GEMM3 split-K: partial[s][M][96] = u[M, ks] @ W_x[ks, :96], u is bf16.
// ----------------------------------------------------------------------------
__global__ __launch_bounds__(256) void gemm3_splitk(
    const u16* __restrict__ ubf, const float* __restrict__ Wx,
    float* __restrict__ partial)
{
    __shared__ float us[64][65];
    __shared__ float wsm[64][96];

    const int tid = threadIdx.x;
    const int r0 = blockIdx.x * 64;
    const int k0 = blockIdx.y * (DINNER / KSPLIT);

    const int orow = tid >> 2;
    const int oc0  = (tid & 3) * 24;

    float acc[24];
    #pragma unroll
    for (int j = 0; j < 24; j++) acc[j] = 0.f;

    for (int ks = 0; ks < DINNER / KSPLIT; ks += 64) {
        {
            const int row = tid >> 2;
            const int c16 = (tid & 3) << 4;
            const uint4* src = reinterpret_cast<const uint4*>(
                ubf + (size_t)(r0 + row) * DINNER + k0 + ks + c16);
            const uint4 q0 = src[0], q1 = src[1];
            const u16* e0 = reinterpret_cast<const u16*>(&q0);
            const u16* e1 = reinterpret_cast<const u16*>(&q1);
            #pragma unroll
            for (int j = 0; j < 8; j++) us[row][c16 + j]     = b2f(e0[j]);
            #pragma unroll
            for (int j = 0; j < 8; j++) us[row][c16 + 8 + j] = b2f(e1[j]);
        }
        #pragma unroll
        for (int j = 0; j < 6; j++) {
            const int fid = tid + j * 256;
            const int kr  = fid / 24;
            const int c4  = (fid % 24) * 4;
            *reinterpret_cast<float4*>(&wsm[kr][c4]) =
                *reinterpret_cast<const float4*>(Wx + (size_t)(k0 + ks + kr) * NX + c4);
        }
        __syncthreads();

        for (int kk = 0; kk < 64; ++kk) {
            const float uv = us[orow][kk];
            #pragma unroll
            for (int j = 0; j < 24; j++)
                acc[j] = fmaf(uv, wsm[kk][oc0 + j], acc[j]);
        }
        __syncthreads();
    }

    float* pp = partial + ((size_t)blockIdx.y * (B_SZ * LSEQ) + r0 + orow) * NX + oc0;
    #pragma unroll
    for (int j = 0; j < 24; j += 4)
        *reinterpret_cast<float4*>(pp + j) = make_float4(acc[j], acc[j+1], acc[j+2], acc[j+3]);
}

// reduce partials -> xdbl f32 [M][96]; also emit bf16 copy of cols 0..63 (GEMM4 A)
__global__ __launch_bounds__(256) void gemm3_reduce(
    const float* __restrict__ partial, float* __restrict__ xdbl,
    u16* __restrict__ x64bf)
{
    const int i = blockIdx.x * 256 + threadIdx.x;   // float4 index over [M][96]
    if (i >= B_SZ * LSEQ * NX / 4) return;
    float4 s = make_float4(0.f, 0.f, 0.f, 0.f);
    #pragma unroll
    for (int p = 0; p < KSPLIT; p++) {
        const float4 v = reinterpret_cast<const float4*>(
            partial + (size_t)p * (B_SZ * LSEQ) * NX)[i];
        s.x += v.x; s.y += v.y; s.z += v.z; s.w += v.w;
    }
    reinterpret_cast<float4*>(xdbl)[i] = s;

    const int col4 = (i % 24) * 4;
    if (col4 < DTRANK) {
        const int row = i / 24;
        union { u16 u[4]; uint2 q; } r;
        r.u[0] = f2b(s.x); r.u[1] = f2b(s.y); r.u[2] = f2b(s.z); r.u[3] = f2b(s.w);
        *reinterpret_cast<uint2*>(x64bf + (size_t)row * DTRANK + col4) = r.q;
    }
}

// ----------------------------------------------------------------------------
// Chunk-parallel selective scan (3 phases). delta comes in as bf16 (dl_bf).
// ----------------------------------------------------------------------------
__global__ __launch_bounds__(256) void scan_phase1(
    const u16* __restrict__ dl_bf, const u16* __restrict__ ubf,
    const float* __restrict__ xdbl, const float* __restrict__ A_log,
    float* __restrict__ hend, float* __restrict__ Sd)
{
    const int idx = blockIdx.x * 256 + threadIdx.x;   // ((b*NCHUNK+c)*DINNER+d)
    const int d = idx & (DINNER - 1);
    const int c = (idx >> 11) & (NCHUNK - 1);
    const int b = idx >> 17;

    float a[DSTATE];
    #pragma unroll
    for (int n = 0; n < DSTATE; n++) a[n] = -__expf(A_log[d * DSTATE + n]);

    float h[DSTATE];
    #pragma unroll
    for (int n = 0; n < DSTATE; n++) h[n] = 0.f;
    float sd = 0.f;

    const int l0 = b * LSEQ + c * CLEN;
    for (int i = 0; i < CLEN; ++i) {
        const size_t r = (size_t)(l0 + i);
        const float dv = b2f(dl_bf[r * DINNER + d]);
        const float uv = b2f(ubf[r * DINNER + d]);
        sd += dv;
        float Bv[DSTATE];
        {
            const float4* bp = reinterpret_cast<const float4*>(xdbl + r * NX + DTRANK);
            float4 q;
            q = bp[0]; Bv[0]=q.x;  Bv[1]=q.y;  Bv[2]=q.z;  Bv[3]=q.w;
            q = bp[1]; Bv[4]=q.x;  Bv[5]=q.y;  Bv[6]=q.z;  Bv[7]=q.w;
            q = bp[2]; Bv[8]=q.x;  Bv[9]=q.y;  Bv[10]=q.z; Bv[11]=q.w;
            q = bp[3]; Bv[12]=q.x; Bv[13]=q.y; Bv[14]=q.z; Bv[15]=q.w;
        }
        const float du = dv * uv;
        #pragma unroll
        for (int n = 0; n < DSTATE; n++)
            h[n] = fmaf(__expf(dv * a[n]), h[n], du * Bv[n]);
    }

    float* hp = hend + ((size_t)(b * DINNER + d) * NCHUNK + c) * DSTATE;
    #pragma unroll
    for (int n = 0; n < DSTATE; n += 4)
        *reinterpret_cast<float4*>(hp + n) = make_float4(h[n], h[n+1], h[n+2], h[n+3]);
    Sd[(size_t)(b * DINNER + d) * NCHUNK + c] = sd;
}

__global__ __launch_bounds__(256) void scan_phase2(
    float* __restrict__ hend, const float* __restrict__ Sd,
    const float* __restrict__ A_log)
{
    const int idx = blockIdx.x * 256 + threadIdx.x;
    if (idx >= B_SZ * DINNER * DSTATE) return;
    const int n = idx & (DSTATE - 1);
    const int d = (idx >> 4) & (DINNER - 1);
    const int b = idx >> 15;

    const float an = -__expf(A_log[d * DSTATE + n]);
    const size_t base = (size_t)(b * DINNER + d) * NCHUNK;
    float carry = 0.f;
    for (int c = 0; c < NCHUNK; ++c) {
        const float P = __expf(an * Sd[base + c]);
        const size_t off = (base + c) * DSTATE + n;
        const float tmp = hend[off];
        hend[off] = carry;
        carry = fmaf(P, carry, tmp);
    }
}

__global__ __launch_bounds__(256) void scan_phase3(
    const u16* __restrict__ dl_bf, const u16* __restrict__ ubf,
    const u16* __restrict__ zs_bf, const float* __restrict__ xdbl,
    const float* __restrict__ A_log, const float* __restrict__ Dp,
    const float* __restrict__ hin, u16* __restrict__ ybf)
{
    const int idx = blockIdx.x * 256 + threadIdx.x;
    const int d = idx & (DINNER - 1);
    const int c = (idx >> 11) & (NCHUNK - 1);
    const int b = idx >> 17;

    float a[DSTATE];
    #pragma unroll
    for (int n = 0; n < DSTATE; n++) a[n] = -__expf(A_log[d * DSTATE + n]);
    const float Dd = Dp[d];

    float h[DSTATE];
    {
        const float* hp = hin + ((size_t)(b * DINNER + d) * NCHUNK + c) * DSTATE;
        #pragma unroll
        for (int n = 0; n < DSTATE; n += 4) {
            const float4 t = *reinterpret_cast<const float4*>(hp + n);
            h[n] = t.x; h[n+1] = t.y; h[n+2] = t.z; h[n+3] = t.w;
        }
    }

    const int l0 = b * LSEQ + c * CLEN;
    for (int i = 0; i < CLEN; ++i) {
        const size_t r = (size_t)(l0 + i);
        const float dv = b2f(dl_bf[r * DINNER + d]);
        const float uv = b2f(ubf[r * DINNER + d]);

        const float4* bp = reinterpret_cast<const float4*>(xdbl + r * NX + DTRANK);
        float Bv[DSTATE], Cv[DSTATE];
        {
            float4 t;
            t = bp[0]; Bv[0]=t.x;  Bv[1]=t.y;  Bv[2]=t.z;  Bv[3]=t.w;
            t = bp[1]; Bv[4]=t.x;  Bv[5]=t.y;  Bv[6]=t.z;  Bv[7]=t.w;
            t = bp[2]; Bv[8]=t.x;  Bv[9]=t.y;  Bv[10]=t.z; Bv[11]=t.w;
            t = bp[3]; Bv[12]=t.x; Bv[13]=t.y; Bv[14]=t.z; Bv[15]=t.w;
            t = bp[4]; Cv[0]=t.x;  Cv[1]=t.y;  Cv[2]=t.z;  Cv[3]=t.w;
            t = bp[5]; Cv[4]=t.x;  Cv[5]=t.y;  Cv[6]=t.z;  Cv[7]=t.w;
            t = bp[6]; Cv[8]=t.x;  Cv[9]=t.y;  Cv[10]=t.z; Cv[11]=t.w;
            t = bp[7]; Cv[12]=t.x; Cv[13]=t.y; Cv[14]=t.z; Cv[15]=t.w;
        }

        const float du = dv * uv;
        float yv = 0.f;
        #pragma unroll
        for (int n = 0; n < DSTATE; n++) {
            h[n] = fmaf(__expf(dv * a[n]), h[n], du * Bv[n]);
            yv = fmaf(h[n], Cv[n], yv);
        }
        yv = fmaf(uv, Dd, yv);

        const float g = b2f(zs_bf[r * DINNER + d]);   // pre-gated silu(res)
        ybf[r * DINNER + d] = f2b(yv * g);
    }
}

// ----------------------------------------------------------------------------
extern "C" void kernel_launch(void* const* d_in, const int* in_sizes, int n_in,
                              void* d_out, int out_size, void* d_ws, size_t ws_size,
                              hipStream_t stream) {
    const float* x      = (const float*)d_in[0];
    const float* W_in   = (const float*)d_in[1];
    const float* conv_w = (const float*)d_in[2];
    const float* conv_b = (const float*)d_in[3];
    const float* W_x    = (const float*)d_in[4];
    const float* W_dt   = (const float*)d_in[5];
    const float* b_dt   = (const float*)d_in[6];
    const float* A_log  = (const float*)d_in[7];
    const float* Dp     = (const float*)d_in[8];
    const float* W_out  = (const float*)d_in[9];
    float* out = (float*)d_out;

    const int M = B_SZ * LSEQ;   // 4096

    // workspace layout (~121 MB)
    float* ws     = (float*)d_ws;
    float* xdbl   = ws;                                           // [4096,96] f32
    float* hend   = xdbl + (size_t)M * NX;                        // [2,2048,64,16] f32
    float* Sd     = hend + (size_t)B_SZ * DINNER * NCHUNK * DSTATE;
    float* part   = Sd   + (size_t)B_SZ * DINNER * NCHUNK;        // [8,4096,96] f32
    u16*   xs_bf  = (u16*)(part + (size_t)KSPLIT * M * NX);       // [4096,2048] bf16
    u16*   zs_bf  = xs_bf + (size_t)M * DINNER;                   // [4096,2048] bf16
    u16*   u_bf   = zs_bf + (size_t)M * DINNER;                   // [4096,2048] bf16
    u16*   dl_bf  = u_bf  + (size_t)M * DINNER;                   // [4096,2048] bf16
    u16*   xbf    = dl_bf + (size_t)M * DINNER;                   // [4096,1024] bf16
    u16*   WinT   = xbf   + (size_t)M * DMODEL;                   // [4096,1024] bf16
    u16*   WoutT  = WinT  + (size_t)M * DMODEL;                   // [1024,2048] bf16
    u16*   x64bf  = WoutT + (size_t)DMODEL * DINNER;              // [4096,64] bf16
    u16*   WdtT   = x64bf + (size_t)M * DTRANK;                   // [2048,64] bf16
    u16*   ybf    = xbf;                                          // aliases xbf+WinT

    dim3 blk(256);

    // 0) casts for GEMM1
    cast_bf16<<<dim3((M * DMODEL / 8) / 256), blk, 0, stream>>>(x, xbf, M * DMODEL / 8);
    castT_bf16<<<dim3((2 * DINNER) / 32, DMODEL / 32), blk, 0, stream>>>(
        W_in, WinT, DMODEL, 2 * DINNER);

    // 1) GEMM1 (256² pipelined + T1): xs_bf + pre-gated zs_bf, both bf16
    gemm1_8ph<<<dim3((2 * DINNER) / 256, M / 256), dim3(512), 131072, stream>>>(
        xbf, WinT, xs_bf, zs_bf);

    // 2) u = silu(causal_conv(xs) + conv_b)
    conv_silu_bf<<<dim3((M * DINNER / 8) / 256), blk, 0, stream>>>(
        xs_bf, conv_w, conv_b, u_bf);

    // 3) xdbl = u @ W_x (split-K); reduce also emits x64bf (GEMM4 A, bf16)
    gemm3_splitk<<<dim3(M / 64, KSPLIT), blk, 0, stream>>>(u_bf, W_x, part);
    gemm3_reduce<<<dim3((M * NX / 4 + 255) / 256), blk, 0, stream>>>(part, xdbl, x64bf);

    // 4) GEMM4 (bf16 MFMA, K=64): dl_bf = bf16(softplus(x64 @ W_dt + b_dt))
    castT_bf16<<<dim3(DINNER / 32, DTRANK / 32), blk, 0, stream>>>(
        W_dt, WdtT, DTRANK, DINNER);
    gemm_mfma<2><<<dim3(DINNER / 128, M / 128), blk, 0, stream>>>(
        x64bf, WdtT, nullptr, dl_bf, nullptr, b_dt, M, DINNER, DTRANK, DINNER);

    // 5) chunk-parallel scan
    scan_phase1<<<dim3((B_SZ * DINNER * NCHUNK) / 256), blk, 0, stream>>>(
        dl_bf, u_bf, xdbl, A_log, hend, Sd);
    scan_phase2<<<dim3((B_SZ * DINNER * DSTATE) / 256), blk, 0, stream>>>(
        hend, Sd, A_log);
    scan_phase3<<<dim3((B_SZ * DINNER * NCHUNK) / 256), blk, 0, stream>>>(
        dl_bf, u_bf, zs_bf, xdbl, A_log, Dp, hend, ybf);

    // 5b) W_out^T cast
    castT_bf16<<<dim3(DMODEL / 32, DINNER / 32), blk, 0, stream>>>(
        W_out, WoutT, DINNER, DMODEL);

    // 6) out = y @ W_out  (bf16 MFMA + T1)
    gemm_mfma<0><<<dim3(DMODEL / 128, M / 128), blk, 0, stream>>>(
        ybf, WoutT, out, nullptr, nullptr, nullptr, M, DMODEL, DINNER, DMODEL);
}